// Round 3
// baseline (984.791 us; speedup 1.0000x reference)
//
#include <hip/hip_runtime.h>
#include <hip/hip_cooperative_groups.h>
#include <hip/hip_bf16.h>
#include <hip/hip_fp16.h>
#include <math.h>

namespace cg = cooperative_groups;

#define HID 64

#if defined(__has_builtin)
#if __has_builtin(__builtin_amdgcn_cvt_pk_f32_fp8) && __has_builtin(__builtin_amdgcn_cvt_pk_fp8_f32)
#define HWFP8 1
#endif
#endif

typedef float vfloat2 __attribute__((ext_vector_type(2)));
typedef __attribute__((ext_vector_type(8))) short short8_t;   // 8 bf16 (4 VGPRs)
typedef __attribute__((ext_vector_type(4))) float f32x4;

union ABFrag { short8_t s; unsigned short u[8]; };

// ---------------- helpers ----------------

__device__ __forceinline__ unsigned short f2bf(float x) {
    unsigned int u = __float_as_uint(x);
    unsigned int r = u + 0x7fffu + ((u >> 16) & 1u);   // RNE
    return (unsigned short)(r >> 16);
}

#ifndef HWFP8
__device__ __forceinline__ unsigned int enc8_sw(float a) {
    unsigned short hb = __half_as_ushort(__float2half(a));
    unsigned int r = (unsigned int)hb + 0x7fu + ((hb >> 8) & 1u);
    return (r >> 8) & 0xffu;
}
__device__ __forceinline__ float dec8_sw(unsigned int b) {
    return __half2float(__ushort_as_half((unsigned short)(b << 8)));
}
#endif

__device__ __forceinline__ unsigned int enc4(float a, float b, float c, float d) {
#ifdef HWFP8
    int r = __builtin_amdgcn_cvt_pk_fp8_f32(a, b, 0, false);
    r = __builtin_amdgcn_cvt_pk_fp8_f32(c, d, r, true);
    return (unsigned int)r;
#else
    return enc8_sw(a) | (enc8_sw(b) << 8) | (enc8_sw(c) << 16) | (enc8_sw(d) << 24);
#endif
}

__device__ __forceinline__ void dec4(unsigned int w, float* f) {
#ifdef HWFP8
    vfloat2 a = __builtin_amdgcn_cvt_pk_f32_fp8((int)w, false);
    vfloat2 b = __builtin_amdgcn_cvt_pk_f32_fp8((int)w, true);
    f[0] = a.x; f[1] = a.y; f[2] = b.x; f[3] = b.y;
#else
    f[0] = dec8_sw(w & 0xffu); f[1] = dec8_sw((w >> 8) & 0xffu);
    f[2] = dec8_sw((w >> 16) & 0xffu); f[3] = dec8_sw(w >> 24);
#endif
}

__device__ __forceinline__ void dec8(uint2 g, float* f) {
    dec4(g.x, f);
    dec4(g.y, f + 4);
}

// =======================================================================
// Cooperative mega-kernel: all phases in one dispatch, grid.sync between.
// =======================================================================

struct MegaArgs {
    const float* x;
    const int* esrc; const int* edst;
    const int* prow; const int* pcol;
    const float* W1; const float* W2; const float* W3;
    const float* b1; const float* b2; const float* b3;
    const float* fcW; const float* fcb;
    const float* l1W; const float* l1b;
    const float* l2W; const float* l2b;
    float* out;
    int* deg; int* fill; int* ccnt; int* cfill;
    float* hpre; float* dinv;
    int* rowoff; int* coff; int* crow;
    float* hpoolT; int* ssrc; float* snorm;
    unsigned int* Yq; unsigned short* X1; unsigned short* X2;
    float* sArr; unsigned short* Wt;
    int N, E, P, NC, HFC, bs, NCLS, rows;
};

// ---- GEMM phase (device fn; identical math to proven k_gemm_mfma) ----
template<int MODE>
__device__ __forceinline__ void gemm_phase(float* sOutAll, const void* Xv,
                                           const unsigned short* Wt,
                                           unsigned int* Yq, float S,
                                           int N, int rowsTot,
                                           int bid, int nB, int tid) {
    int w = tid >> 6, lane = tid & 63;
    int nT = (rowsTot + 63) >> 6;
    const float* Xf = (const float*)Xv;
    const unsigned short* Xh = (const unsigned short*)Xv;
    float* so = sOutAll + w * (16 * 68);
    int cc = lane & 15;
    int kg = (lane >> 4) * 8;
    int cr = (lane >> 4) * 4;

    for (int tile = bid; tile < nT; tile += nB) {
        int r0w = tile * 64 + w * 16;
        int rA = r0w + (lane & 15);
        f32x4 acc[4] = {f32x4{}, f32x4{}, f32x4{}, f32x4{}};
#pragma unroll
        for (int k0 = 0; k0 < 64; k0 += 32) {
            ABFrag a;
            if (rA < rowsTot) {
                if (MODE == 0) {
                    int n = rA >> 3, b = rA & 7;
                    const float* p = &Xf[((size_t)b * N + n) * 64 + k0 + kg];
                    float4 v0 = *(const float4*)p;
                    float4 v1 = *(const float4*)(p + 4);
                    a.u[0] = f2bf(v0.x); a.u[1] = f2bf(v0.y);
                    a.u[2] = f2bf(v0.z); a.u[3] = f2bf(v0.w);
                    a.u[4] = f2bf(v1.x); a.u[5] = f2bf(v1.y);
                    a.u[6] = f2bf(v1.z); a.u[7] = f2bf(v1.w);
                } else {
                    a.s = *(const short8_t*)&Xh[(size_t)rA * 64 + k0 + kg];
                }
            } else {
#pragma unroll
                for (int j = 0; j < 8; ++j) a.u[j] = 0;
            }
#pragma unroll
            for (int c = 0; c < 4; ++c) {
                ABFrag b;
                b.s = *(const short8_t*)&Wt[(size_t)(c * 16 + cc) * 64 + k0 + kg];
                acc[c] = __builtin_amdgcn_mfma_f32_16x16x32_bf16(a.s, b.s, acc[c], 0, 0, 0);
            }
        }
        // per-wave LDS transpose epilogue
#pragma unroll
        for (int c = 0; c < 4; ++c) {
            so[(cr + 0) * 68 + c * 16 + cc] = acc[c][0];
            so[(cr + 1) * 68 + c * 16 + cc] = acc[c][1];
            so[(cr + 2) * 68 + c * 16 + cc] = acc[c][2];
            so[(cr + 3) * 68 + c * 16 + cc] = acc[c][3];
        }
        __syncthreads();
#pragma unroll
        for (int i = 0; i < 4; ++i) {
            int idx = lane + i * 64;
            int row = idx >> 4, ci = idx & 15;
            int grow = r0w + row;
            if (grow < rowsTot) {
                float4 v = *(const float4*)&so[row * 68 + ci * 4];
                Yq[(size_t)grow * 16 + ci] =
                    enc4(v.x * S, v.y * S, v.z * S, v.w * S);
            }
        }
        __syncthreads();
    }
}

// ---- AGG phase (device fn; identical math to proven k_agg) ----
template<int LAYER, bool STORE>
__device__ __forceinline__ void agg_phase(const uint2* Y, const int* rowoff,
                                          const int* ssrc, const float* snorm,
                                          const float* dinv, const float* bias,
                                          const float* fcW, uint4* O, float* sArr,
                                          float invS, int N,
                                          int bid, int nB, int tid) {
    int w = tid >> 6, lane = tid & 63;
    int nG = (N + 3) >> 2;
    int hb = (lane & 7) * 8;
    float bv[8], wv[8];
#pragma unroll
    for (int k = 0; k < 8; ++k) { bv[k] = bias[hb + k]; wv[k] = fcW[3 * (hb + k) + LAYER]; }

    for (int g = bid; g < nG; g += nB) {
        int n = g * 4 + w;
        if (n < N) {
            float dn = dinv[n];
            float w0 = dn * dn;
            float acc[8], f[8];
            dec8(Y[(size_t)n * 64 + lane], f);
#pragma unroll
            for (int k = 0; k < 8; ++k) acc[k] = w0 * f[k];

            int beg = rowoff[n], end = rowoff[n + 1];
            int i = beg;
            for (; i + 7 < end; i += 8) {
                int   sI[8];
                float wI[8];
                uint2 gg[8];
#pragma unroll
                for (int u = 0; u < 8; ++u) { sI[u] = ssrc[i + u]; wI[u] = snorm[i + u]; }
#pragma unroll
                for (int u = 0; u < 8; ++u) gg[u] = Y[(size_t)sI[u] * 64 + lane];
#pragma unroll
                for (int u = 0; u < 8; ++u) {
                    dec8(gg[u], f);
#pragma unroll
                    for (int k = 0; k < 8; ++k) acc[k] = fmaf(wI[u], f[k], acc[k]);
                }
            }
            for (; i < end; ++i) {
                int s = ssrc[i];
                float ww = snorm[i];
                dec8(Y[(size_t)s * 64 + lane], f);
#pragma unroll
                for (int k = 0; k < 8; ++k) acc[k] = fmaf(ww, f[k], acc[k]);
            }

            float sv = 0.f;
#pragma unroll
            for (int k = 0; k < 8; ++k) {
                float o = fmaxf(fmaf(acc[k], invS, bv[k]), 0.f);
                acc[k] = o;
                sv = fmaf(o, wv[k], sv);
            }
            if (STORE) {
                uint4 o;
                o.x = (unsigned int)f2bf(acc[0]) | ((unsigned int)f2bf(acc[1]) << 16);
                o.y = (unsigned int)f2bf(acc[2]) | ((unsigned int)f2bf(acc[3]) << 16);
                o.z = (unsigned int)f2bf(acc[4]) | ((unsigned int)f2bf(acc[5]) << 16);
                o.w = (unsigned int)f2bf(acc[6]) | ((unsigned int)f2bf(acc[7]) << 16);
                O[(size_t)n * 64 + lane] = o;
            }
            sv += __shfl_down(sv, 4, 64);
            sv += __shfl_down(sv, 2, 64);
            sv += __shfl_down(sv, 1, 64);
            if ((lane & 7) == 0) {
                int b = lane >> 3;
                float* sp = sArr + (size_t)n * 8 + b;
                if (LAYER == 0) *sp = sv;
                else            *sp += sv;
            }
        }
    }
}

union SmemU {
    float sOut[4 * 16 * 68];        // gemm epilogue (17408 B)
    int   part[256];                // scan
    float hl2[2][64];               // l1 partial (two 128-thread jobs)
    float sZ[64];                   // final head
};

__global__ __launch_bounds__(256, 4) void k_mega(MegaArgs A) {
    cg::grid_group grid = cg::this_grid();
    __shared__ SmemU sm;
    int tid = threadIdx.x;
    int bid = blockIdx.x;
    int nB  = gridDim.x;
    int GT  = nB * 256;
    int gth = bid * 256 + tid;
    int w = tid >> 6, lane = tid & 63;

    // ---- P0: degree/col counts + Wt convert ----
    for (int e = gth; e < A.E; e += GT) atomicAdd(&A.deg[A.edst[e]], 1);
    for (int p = gth; p < A.P; p += GT) atomicAdd(&A.ccnt[A.pcol[p]], 1);
    for (int i = gth; i < 3 * 4096; i += GT) {
        int l = i >> 12, r = i & 4095;
        int k = r >> 6, c = r & 63;
        const float* W = (l == 0) ? A.W1 : (l == 1) ? A.W2 : A.W3;
        A.Wt[(l << 12) + c * 64 + k] = f2bf(W[r]);
    }
    grid.sync();

    // ---- P1: dinv + exclusive scans (blocks 0,1) ----
    for (int i = gth; i < A.N; i += GT) A.dinv[i] = rsqrtf((float)(A.deg[i] + 1));
    if (bid < 2) {
        const int* cnt; int* off; int n;
        if (bid == 0) { cnt = A.deg;  off = A.rowoff; n = A.N; }
        else          { cnt = A.ccnt; off = A.coff;   n = A.NC; }
        int t = tid;
        int CH = (n + 255) >> 8;
        int lo = min(t * CH, n), hi = min(lo + CH, n);
        int sum = 0;
        for (int i = lo; i < hi; ++i) sum += cnt[i];
        sm.part[t] = sum;
        __syncthreads();
        for (int o = 1; o < 256; o <<= 1) {
            int v = (t >= o) ? sm.part[t - o] : 0;
            __syncthreads();
            sm.part[t] += v;
            __syncthreads();
        }
        int run = (t == 0) ? 0 : sm.part[t - 1];
        for (int i = lo; i < hi; ++i) { off[i] = run; run += cnt[i]; }
        if (t == 255) off[n] = run;
    }
    grid.sync();

    // ---- P2: CSR/CSC scatter ----
    for (int e = gth; e < A.E; e += GT) {
        int s = A.esrc[e], d = A.edst[e];
        int pos = A.rowoff[d] + atomicAdd(&A.fill[d], 1);
        A.ssrc[pos]  = s;
        A.snorm[pos] = A.dinv[s] * A.dinv[d];
    }
    for (int p = gth; p < A.P; p += GT) {
        int c = A.pcol[p];
        int pos = A.coff[c] + atomicAdd(&A.cfill[c], 1);
        A.crow[pos] = A.prow[p];
    }
    grid.sync();

    const float S1 = 1.f,   iS1 = 1.f;
    const float S2 = 16.f,  iS2 = 1.f / 16.f;
    const float S3 = 128.f, iS3 = 1.f / 128.f;

    // ---- 3 GCN layers ----
    gemm_phase<0>(sm.sOut, A.x, A.Wt, A.Yq, S1, A.N, A.rows, bid, nB, tid);
    grid.sync();
    agg_phase<0, true>((const uint2*)A.Yq, A.rowoff, A.ssrc, A.snorm, A.dinv, A.b1, A.fcW,
                       (uint4*)A.X1, A.sArr, iS1, A.N, bid, nB, tid);
    grid.sync();
    gemm_phase<1>(sm.sOut, A.X1, A.Wt + 4096, A.Yq, S2, A.N, A.rows, bid, nB, tid);
    grid.sync();
    agg_phase<1, true>((const uint2*)A.Yq, A.rowoff, A.ssrc, A.snorm, A.dinv, A.b2, A.fcW,
                       (uint4*)A.X2, A.sArr, iS2, A.N, bid, nB, tid);
    grid.sync();
    gemm_phase<1>(sm.sOut, A.X2, A.Wt + 8192, A.Yq, S3, A.N, A.rows, bid, nB, tid);
    grid.sync();
    agg_phase<2, false>((const uint2*)A.Yq, A.rowoff, A.ssrc, A.snorm, A.dinv, A.b3, A.fcW,
                        nullptr, A.sArr, iS3, A.N, bid, nB, tid);
    grid.sync();

    // ---- pool: one wave per pathway column ----
    for (int c = bid * 4 + w; c < A.NC; c += nB * 4) {
        int beg = A.coff[c], end = A.coff[c + 1];
        int b = lane & 7;
        float acc = 0.f;
        int i = beg + (lane >> 3);
        for (; i + 24 < end; i += 32) {
            int r0 = A.crow[i], r1 = A.crow[i + 8], r2 = A.crow[i + 16], r3 = A.crow[i + 24];
            float a0 = A.sArr[(size_t)r0 * 8 + b];
            float a1 = A.sArr[(size_t)r1 * 8 + b];
            float a2 = A.sArr[(size_t)r2 * 8 + b];
            float a3 = A.sArr[(size_t)r3 * 8 + b];
            acc += (a0 + a1) + (a2 + a3);
        }
        for (; i < end; i += 8) acc += A.sArr[(size_t)A.crow[i] * 8 + b];
        acc += __shfl_down(acc, 32, 64);
        acc += __shfl_down(acc, 16, 64);
        acc += __shfl_down(acc, 8, 64);
        if (lane < 8) {
            float inv = 1.f / fmaxf((float)(end - beg), 1.f);
            A.hpoolT[(size_t)c * 8 + b] = acc * inv;
        }
    }
    grid.sync();

    // ---- l1 partial: 200 (chunk,b) jobs of 128 threads; 2 jobs/block ----
    {
        const int CHUNK = 40;
        int gx25 = (A.NC + CHUNK - 1) / CHUNK;        // 25
        int nJobs = gx25 * A.bs;                      // 200 (even)
        int h = tid >> 7, j = tid & 127;
        float fcb0 = A.fcb[0];
        for (int jj = bid * 2; jj < nJobs; jj += nB * 2) {
            int J = jj + h;                           // nJobs even -> always valid
            int gx = J % gx25, b = J / gx25;
            int c0 = gx * CHUNK;
            int cend = min(c0 + CHUNK, A.NC);
            float* hl = sm.hl2[h];
            for (int c = c0 + j; c < cend; c += 128)
                hl[c - c0] = A.hpoolT[(size_t)c * 8 + b] + fcb0;
            __syncthreads();
            float acc = 0.f;
            for (int c = c0; c < cend; ++c)
                acc = fmaf(hl[c - c0], A.l1W[(size_t)c * A.HFC + j], acc);
            atomicAdd(&A.hpre[(size_t)b * A.HFC + j], acc);
            __syncthreads();
        }
    }
    grid.sync();

    // ---- final: relu(l1) -> l2 -> log_softmax (block 0) ----
    if (bid == 0) {
        int j = tid;
        int g = j >> 3, l8 = j & 7;
        int nout = A.bs * A.NCLS;
        float v = 0.f;
        int b2 = g / A.NCLS, k2 = g - b2 * A.NCLS;
        if (g < nout) {
            for (int jj2 = l8; jj2 < A.HFC; jj2 += 8) {
                float hh = fmaxf(A.hpre[(size_t)b2 * A.HFC + jj2] + A.l1b[jj2], 0.f);
                v = fmaf(hh, A.l2W[(size_t)jj2 * A.NCLS + k2], v);
            }
        }
        v += __shfl_down(v, 4, 8);
        v += __shfl_down(v, 2, 8);
        v += __shfl_down(v, 1, 8);
        if (l8 == 0 && g < nout) sm.sZ[g] = v + A.l2b[k2];
        __syncthreads();
        if (j < A.bs) {
            float m = -1e30f;
            for (int c = 0; c < A.NCLS; ++c) m = fmaxf(m, sm.sZ[j * A.NCLS + c]);
            float s = 0.f;
            for (int c = 0; c < A.NCLS; ++c) s += expf(sm.sZ[j * A.NCLS + c] - m);
            float lse = m + logf(s);
            for (int c = 0; c < A.NCLS; ++c) A.out[j * A.NCLS + c] = sm.sZ[j * A.NCLS + c] - lse;
        }
    }
}

// =======================================================================
// Fallback path: the proven 12-dispatch pipeline (unchanged from R2).
// =======================================================================

__global__ __launch_bounds__(256) void k_pre_count(const int* __restrict__ edst, int* __restrict__ deg, int E,
                                                   const int* __restrict__ pcol, int* __restrict__ ccnt, int P,
                                                   const float* __restrict__ W1, const float* __restrict__ W2,
                                                   const float* __restrict__ W3, unsigned short* __restrict__ Wt) {
    int gth = blockIdx.x * blockDim.x + threadIdx.x;
    int GT = gridDim.x * blockDim.x;
    for (int e = gth; e < E; e += GT) atomicAdd(&deg[edst[e]], 1);
    for (int p = gth; p < P; p += GT) atomicAdd(&ccnt[pcol[p]], 1);
    for (int i = gth; i < 3 * 4096; i += GT) {
        int l = i >> 12, r = i & 4095;
        int k = r >> 6, c = r & 63;
        const float* W = (l == 0) ? W1 : (l == 1) ? W2 : W3;
        Wt[(l << 12) + c * 64 + k] = f2bf(W[r]);
    }
}

__global__ __launch_bounds__(256) void k_pre_scan(const int* __restrict__ deg, int* __restrict__ rowoff, int N,
                                                  const int* __restrict__ ccnt, int* __restrict__ coff, int NC,
                                                  float* __restrict__ dinv) {
    __shared__ int part[256];
    int t = threadIdx.x;
    int gth = blockIdx.x * blockDim.x + t;
    int GT = gridDim.x * blockDim.x;
    for (int i = gth; i < N; i += GT) dinv[i] = rsqrtf((float)(deg[i] + 1));

    const int* cnt = nullptr; int* off = nullptr; int n = 0;
    if (blockIdx.x == 0)      { cnt = deg;  off = rowoff; n = N; }
    else if (blockIdx.x == 1) { cnt = ccnt; off = coff;   n = NC; }
    else return;

    int CH = (n + 255) >> 8;
    int lo = min(t * CH, n), hi = min(lo + CH, n);
    int sum = 0;
    for (int i = lo; i < hi; ++i) sum += cnt[i];
    part[t] = sum;
    __syncthreads();
    for (int o = 1; o < 256; o <<= 1) {
        int v = (t >= o) ? part[t - o] : 0;
        __syncthreads();
        part[t] += v;
        __syncthreads();
    }
    int run = (t == 0) ? 0 : part[t - 1];
    for (int i = lo; i < hi; ++i) { off[i] = run; run += cnt[i]; }
    if (t == 255) off[n] = run;
}

__global__ __launch_bounds__(256) void k_pre_scatter(const int* __restrict__ esrc, const int* __restrict__ edst,
                                                     const float* __restrict__ dinv, const int* __restrict__ rowoff,
                                                     int* __restrict__ fill, int* __restrict__ ssrc,
                                                     float* __restrict__ snorm, int E,
                                                     const int* __restrict__ prow, const int* __restrict__ pcol,
                                                     const int* __restrict__ coff, int* __restrict__ cfill,
                                                     int* __restrict__ crow, int P) {
    int gth = blockIdx.x * blockDim.x + threadIdx.x;
    int GT = gridDim.x * blockDim.x;
    for (int e = gth; e < E; e += GT) {
        int s = esrc[e], d = edst[e];
        int pos = rowoff[d] + atomicAdd(&fill[d], 1);
        ssrc[pos]  = s;
        snorm[pos] = dinv[s] * dinv[d];
    }
    for (int p = gth; p < P; p += GT) {
        int c = pcol[p];
        int pos = coff[c] + atomicAdd(&cfill[c], 1);
        crow[pos] = prow[p];
    }
}

template<int MODE>
__global__ __launch_bounds__(256) void k_gemm_mfma(const void* __restrict__ Xv,
                                                   const unsigned short* __restrict__ Wt,
                                                   unsigned int* __restrict__ Yq,
                                                   float S, int N, int rowsTot) {
    __shared__ float sOut[4][16 * 68];
    gemm_phase<MODE>(&sOut[0][0], Xv, Wt, Yq, S, N, rowsTot, blockIdx.x, gridDim.x, threadIdx.x);
}

template<int LAYER, bool STORE>
__global__ __launch_bounds__(256) void k_agg(const uint2* __restrict__ Y,
                                             const int* __restrict__ rowoff,
                                             const int* __restrict__ ssrc,
                                             const float* __restrict__ snorm,
                                             const float* __restrict__ dinv,
                                             const float* __restrict__ bias,
                                             const float* __restrict__ fcW,
                                             uint4* __restrict__ O,
                                             float* __restrict__ sArr,
                                             float invS, int N) {
    agg_phase<LAYER, STORE>(Y, rowoff, ssrc, snorm, dinv, bias, fcW, O, sArr, invS, N,
                            blockIdx.x, gridDim.x, threadIdx.x);
}

__global__ __launch_bounds__(64) void k_poolg(const float* __restrict__ sArr,
                                              const int* __restrict__ coff,
                                              const int* __restrict__ crow,
                                              float* __restrict__ hpoolT) {
    int c = blockIdx.x;
    int lane = threadIdx.x;
    int beg = coff[c], end = coff[c + 1];
    int b = lane & 7;
    float acc = 0.f;
    int i = beg + (lane >> 3);
    for (; i + 24 < end; i += 32) {
        int r0 = crow[i], r1 = crow[i + 8], r2 = crow[i + 16], r3 = crow[i + 24];
        float a0 = sArr[(size_t)r0 * 8 + b];
        float a1 = sArr[(size_t)r1 * 8 + b];
        float a2 = sArr[(size_t)r2 * 8 + b];
        float a3 = sArr[(size_t)r3 * 8 + b];
        acc += (a0 + a1) + (a2 + a3);
    }
    for (; i < end; i += 8) acc += sArr[(size_t)crow[i] * 8 + b];
    acc += __shfl_down(acc, 32, 64);
    acc += __shfl_down(acc, 16, 64);
    acc += __shfl_down(acc, 8, 64);
    if (lane < 8) {
        float inv = 1.f / fmaxf((float)(end - beg), 1.f);
        hpoolT[(size_t)c * 8 + b] = acc * inv;
    }
}

__global__ __launch_bounds__(128) void k_l1f(const float* __restrict__ hpoolT,
                                             const float* __restrict__ fcb,
                                             const float* __restrict__ l1W,
                                             float* __restrict__ hpre,
                                             int* __restrict__ done,
                                             const float* __restrict__ l1b,
                                             const float* __restrict__ l2W,
                                             const float* __restrict__ l2b,
                                             float* __restrict__ out,
                                             int NC, int HFC, int bs, int NCLS,
                                             int CHUNK, int nBlocks) {
    __shared__ float hl[64];
    int b = blockIdx.y;
    int c0 = blockIdx.x * CHUNK;
    int j = threadIdx.x;
    int cend = min(c0 + CHUNK, NC);
    for (int c = c0 + j; c < cend; c += blockDim.x)
        hl[c - c0] = hpoolT[(size_t)c * 8 + b] + fcb[0];
    __syncthreads();
    float acc = 0.f;
    for (int c = c0; c < cend; ++c) acc = fmaf(hl[c - c0], l1W[(size_t)c * HFC + j], acc);
    atomicAdd(&hpre[(size_t)b * HFC + j], acc);

    __threadfence();
    __syncthreads();
    __shared__ int amLast;
    if (j == 0) amLast = (atomicAdd(done, 1) == nBlocks - 1);
    __syncthreads();
    if (!amLast) return;
    __threadfence();

    __shared__ float sZ[64];
    int g = j >> 3, l8 = j & 7;
    int nout = bs * NCLS;
    float v = 0.f;
    int b2 = g / NCLS, k2 = g - b2 * NCLS;
    if (g < nout) {
        for (int jj = l8; jj < HFC; jj += 8) {
            float h = fmaxf(hpre[(size_t)b2 * HFC + jj] + l1b[jj], 0.f);
            v = fmaf(h, l2W[(size_t)jj * NCLS + k2], v);
        }
    }
    v += __shfl_down(v, 4, 8);
    v += __shfl_down(v, 2, 8);
    v += __shfl_down(v, 1, 8);
    if (l8 == 0 && g < nout) sZ[g] = v + l2b[k2];
    __syncthreads();
    if (j < bs) {
        float m = -1e30f;
        for (int c = 0; c < NCLS; ++c) m = fmaxf(m, sZ[j * NCLS + c]);
        float s = 0.f;
        for (int c = 0; c < NCLS; ++c) s += expf(sZ[j * NCLS + c] - m);
        float lse = m + logf(s);
        for (int c = 0; c < NCLS; ++c) out[j * NCLS + c] = sZ[j * NCLS + c] - lse;
    }
}

// ---------------- launcher ----------------

extern "C" void kernel_launch(void* const* d_in, const int* in_sizes, int n_in,
                              void* d_out, int out_size, void* d_ws, size_t ws_size,
                              hipStream_t stream) {
    const float* x   = (const float*)d_in[0];
    const int* eidx  = (const int*)d_in[2];
    const int* prow  = (const int*)d_in[3];
    const int* pcol  = (const int*)d_in[4];
    const float* W1  = (const float*)d_in[5];
    const float* b1  = (const float*)d_in[6];
    const float* W2  = (const float*)d_in[7];
    const float* b2  = (const float*)d_in[8];
    const float* W3  = (const float*)d_in[9];
    const float* b3  = (const float*)d_in[10];
    const float* fcW = (const float*)d_in[11];
    const float* fcb = (const float*)d_in[12];
    const float* l1W = (const float*)d_in[13];
    const float* l1b = (const float*)d_in[14];
    const float* l2W = (const float*)d_in[15];
    const float* l2b = (const float*)d_in[16];
    float* out = (float*)d_out;

    const int bs   = in_sizes[1];                 // 8
    const int E    = in_sizes[2] / 2;
    const int P    = in_sizes[3];
    const int N    = in_sizes[0] / (bs * HID);
    const int HFC  = in_sizes[14];                // 128
    const int NC   = in_sizes[13] / HFC;          // 1000
    const int NCLS = in_sizes[15] / HFC;          // 2
    const int rows = N * bs;

    const int* esrc = eidx;
    const int* edst = eidx + E;

    size_t off = 0;
    auto alloc = [&](size_t bytes) -> void* {
        void* r = (char*)d_ws + off;
        off += (bytes + 255) & ~(size_t)255;
        return r;
    };
    char* zbase   = (char*)d_ws;
    int*   deg    = (int*)  alloc((size_t)N * 4);
    int*   fill   = (int*)  alloc((size_t)N * 4);
    int*   ccnt   = (int*)  alloc((size_t)NC * 4);
    int*   cfill  = (int*)  alloc((size_t)NC * 4);
    float* hpre   = (float*)alloc((size_t)bs * HFC * 4);
    int*   done   = (int*)  alloc(4);
    size_t zspan  = off;
    float* dinv   = (float*)alloc((size_t)N * 4);
    int*   rowoff = (int*)  alloc(((size_t)N + 1) * 4);
    int*   coff   = (int*)  alloc(((size_t)NC + 1) * 4);
    int*   crow   = (int*)  alloc((size_t)P * 4);
    float* hpoolT = (float*)alloc((size_t)NC * bs * 4);
    int*   ssrc   = (int*)  alloc((size_t)E * 4);
    float* snorm  = (float*)alloc((size_t)E * 4);
    unsigned int* Yq   = (unsigned int*)alloc((size_t)rows * HID);
    unsigned short* X1 = (unsigned short*)alloc((size_t)rows * HID * 2);
    unsigned short* X2 = (unsigned short*)alloc((size_t)rows * HID * 2);
    float* sArr   = (float*)alloc((size_t)rows * 4);
    unsigned short* Wt = (unsigned short*)alloc((size_t)3 * 64 * 64 * 2);

    hipMemsetAsync(zbase, 0, zspan, stream);

    // ---- cooperative mega-kernel path ----
    MegaArgs A;
    A.x = x; A.esrc = esrc; A.edst = edst; A.prow = prow; A.pcol = pcol;
    A.W1 = W1; A.W2 = W2; A.W3 = W3; A.b1 = b1; A.b2 = b2; A.b3 = b3;
    A.fcW = fcW; A.fcb = fcb; A.l1W = l1W; A.l1b = l1b; A.l2W = l2W; A.l2b = l2b;
    A.out = out;
    A.deg = deg; A.fill = fill; A.ccnt = ccnt; A.cfill = cfill;
    A.hpre = hpre; A.dinv = dinv; A.rowoff = rowoff; A.coff = coff; A.crow = crow;
    A.hpoolT = hpoolT; A.ssrc = ssrc; A.snorm = snorm;
    A.Yq = Yq; A.X1 = X1; A.X2 = X2; A.sArr = sArr; A.Wt = Wt;
    A.N = N; A.E = E; A.P = P; A.NC = NC; A.HFC = HFC; A.bs = bs; A.NCLS = NCLS; A.rows = rows;

    int maxB = 0;
    hipError_t occErr = hipOccupancyMaxActiveBlocksPerMultiprocessor(&maxB, k_mega, 256, 0);
    if (occErr != hipSuccess || maxB < 1) maxB = 1;
    int nB = maxB * 256;
    if (nB > 1024) nB = 1024;
    if (nB < 2) nB = 2;

    void* kargs[] = { (void*)&A };
    hipError_t err = hipLaunchCooperativeKernel((const void*)k_mega, dim3(nB), dim3(256),
                                                kargs, 0, stream);
    if (err == hipSuccess) return;

    // ---- fallback: proven 12-dispatch pipeline ----
    int gPre = 512;
    k_pre_count<<<gPre, 256, 0, stream>>>(edst, deg, E, pcol, ccnt, P, W1, W2, W3, Wt);
    k_pre_scan<<<64, 256, 0, stream>>>(deg, rowoff, N, ccnt, coff, NC, dinv);
    k_pre_scatter<<<gPre, 256, 0, stream>>>(esrc, edst, dinv, rowoff, fill, ssrc, snorm, E,
                                            prow, pcol, coff, cfill, crow, P);

    const float S1 = 1.f,  iS1 = 1.f;
    const float S2 = 16.f, iS2 = 1.f / 16.f;
    const float S3 = 128.f, iS3 = 1.f / 128.f;

    int gG = (rows + 63) / 64;
    int gA = (N + 3) / 4;
    k_gemm_mfma<0><<<gG, 256, 0, stream>>>(x, Wt, Yq, S1, N, rows);
    k_agg<0, true><<<gA, 256, 0, stream>>>((const uint2*)Yq, rowoff, ssrc, snorm, dinv, b1, fcW, (uint4*)X1, sArr, iS1, N);
    k_gemm_mfma<1><<<gG, 256, 0, stream>>>(X1, Wt + 4096, Yq, S2, N, rows);
    k_agg<1, true><<<gA, 256, 0, stream>>>((const uint2*)Yq, rowoff, ssrc, snorm, dinv, b2, fcW, (uint4*)X2, sArr, iS2, N);
    k_gemm_mfma<1><<<gG, 256, 0, stream>>>(X2, Wt + 8192, Yq, S3, N, rows);
    k_agg<2, false><<<gA, 256, 0, stream>>>((const uint2*)Yq, rowoff, ssrc, snorm, dinv, b3, fcW, nullptr, sArr, iS3, N);

    k_poolg<<<NC, 64, 0, stream>>>(sArr, coff, crow, hpoolT);

    const int CHUNK = 40;
    dim3 gL1((NC + CHUNK - 1) / CHUNK, bs);
    int nBlocks = gL1.x * gL1.y;
    k_l1f<<<gL1, 128, 0, stream>>>(hpoolT, fcb, l1W, hpre, done, l1b, l2W, l2b, out,
                                   NC, HFC, bs, NCLS, CHUNK, nBlocks);
}

// Round 4
// 368.061 us; speedup vs baseline: 2.6756x; 2.6756x over previous
//
#include <hip/hip_runtime.h>
#include <hip/hip_bf16.h>
#include <hip/hip_fp16.h>
#include <math.h>

#define HID 64

#if defined(__has_builtin)
#if __has_builtin(__builtin_amdgcn_cvt_pk_f32_fp8) && __has_builtin(__builtin_amdgcn_cvt_pk_fp8_f32)
#define HWFP8 1
#endif
#endif

typedef float vfloat2 __attribute__((ext_vector_type(2)));
typedef __attribute__((ext_vector_type(8))) short short8_t;   // 8 bf16 (4 VGPRs)
typedef __attribute__((ext_vector_type(4))) float f32x4;

union ABFrag { short8_t s; unsigned short u[8]; };

// ---------------- helpers ----------------

__device__ __forceinline__ unsigned short f2bf(float x) {
    unsigned int u = __float_as_uint(x);
    unsigned int r = u + 0x7fffu + ((u >> 16) & 1u);   // RNE
    return (unsigned short)(r >> 16);
}

#ifndef HWFP8
__device__ __forceinline__ unsigned int enc8_sw(float a) {
    unsigned short hb = __half_as_ushort(__float2half(a));
    unsigned int r = (unsigned int)hb + 0x7fu + ((hb >> 8) & 1u);
    return (r >> 8) & 0xffu;
}
__device__ __forceinline__ float dec8_sw(unsigned int b) {
    return __half2float(__ushort_as_half((unsigned short)(b << 8)));
}
#endif

__device__ __forceinline__ unsigned int enc4(float a, float b, float c, float d) {
#ifdef HWFP8
    int r = __builtin_amdgcn_cvt_pk_fp8_f32(a, b, 0, false);
    r = __builtin_amdgcn_cvt_pk_fp8_f32(c, d, r, true);
    return (unsigned int)r;
#else
    return enc8_sw(a) | (enc8_sw(b) << 8) | (enc8_sw(c) << 16) | (enc8_sw(d) << 24);
#endif
}

__device__ __forceinline__ void dec4(unsigned int w, float* f) {
#ifdef HWFP8
    vfloat2 a = __builtin_amdgcn_cvt_pk_f32_fp8((int)w, false);
    vfloat2 b = __builtin_amdgcn_cvt_pk_f32_fp8((int)w, true);
    f[0] = a.x; f[1] = a.y; f[2] = b.x; f[3] = b.y;
#else
    f[0] = dec8_sw(w & 0xffu); f[1] = dec8_sw((w >> 8) & 0xffu);
    f[2] = dec8_sw((w >> 16) & 0xffu); f[3] = dec8_sw(w >> 24);
#endif
}

__device__ __forceinline__ void dec8(uint2 g, float* f) {
    dec4(g.x, f);
    dec4(g.y, f + 4);
}

// ---------------- GEMM phase (proven R2 device fn, layers 2/3) ----------------
// Y[row, h] = (sum_k X[row, k] * W[k, h]) * S, Y stored fp8. X bf16 [row, k].
// Fragment layouts (gfx950, learn_hip m89-verified C/D):
//   A: row = lane&15, k = (lane>>4)*8 + j ; B: col = lane&15, same k
//   D: col = lane&15, row = (lane>>4)*4 + reg
__device__ __forceinline__ void gemm_bf16_phase(float* so4, const unsigned short* Xh,
                                                const unsigned short* Wt,
                                                unsigned int* Yq, float S,
                                                int rowsTot, int tile, int tid) {
    int w = tid >> 6, lane = tid & 63;
    float* so = so4 + w * (16 * 68);
    int cc = lane & 15;
    int kg = (lane >> 4) * 8;
    int cr = (lane >> 4) * 4;
    int r0w = tile * 64 + w * 16;
    int rA = r0w + (lane & 15);
    f32x4 acc[4] = {f32x4{}, f32x4{}, f32x4{}, f32x4{}};
#pragma unroll
    for (int k0 = 0; k0 < 64; k0 += 32) {
        ABFrag a;
        if (rA < rowsTot) {
            a.s = *(const short8_t*)&Xh[(size_t)rA * 64 + k0 + kg];
        } else {
#pragma unroll
            for (int j = 0; j < 8; ++j) a.u[j] = 0;
        }
#pragma unroll
        for (int c = 0; c < 4; ++c) {
            ABFrag b;
            b.s = *(const short8_t*)&Wt[(size_t)(c * 16 + cc) * 64 + k0 + kg];
            acc[c] = __builtin_amdgcn_mfma_f32_16x16x32_bf16(a.s, b.s, acc[c], 0, 0, 0);
        }
    }
#pragma unroll
    for (int c = 0; c < 4; ++c) {
        so[(cr + 0) * 68 + c * 16 + cc] = acc[c][0];
        so[(cr + 1) * 68 + c * 16 + cc] = acc[c][1];
        so[(cr + 2) * 68 + c * 16 + cc] = acc[c][2];
        so[(cr + 3) * 68 + c * 16 + cc] = acc[c][3];
    }
    __syncthreads();
#pragma unroll
    for (int i = 0; i < 4; ++i) {
        int idx = lane + i * 64;
        int row = idx >> 4, ci = idx & 15;
        int grow = r0w + row;
        if (grow < rowsTot) {
            float4 v = *(const float4*)&so[row * 68 + ci * 4];
            Yq[(size_t)grow * 16 + ci] =
                enc4(v.x * S, v.y * S, v.z * S, v.w * S);
        }
    }
}

template<int DUMMY>
__global__ __launch_bounds__(256) void k_gemm_mfma(const unsigned short* __restrict__ Xh,
                                                   const unsigned short* __restrict__ Wt,
                                                   unsigned int* __restrict__ Yq,
                                                   float S, int rowsTot) {
    __shared__ float sOut[4][16 * 68];
    gemm_bf16_phase(&sOut[0][0], Xh, Wt, Yq, S, rowsTot, blockIdx.x, threadIdx.x);
}

// ---------------- fused dispatch 1: GEMM1 (x fp32, W1 from regs) || pre-count ----------------
// Blocks [0, gG): layer-1 GEMM tile. Blocks [gG, gG+512): degree/col counts +
// Wt conversion for W2/W3 (layer2 at Wt+0, layer3 at Wt+4096). The two halves
// touch disjoint data -> true concurrency, no barrier needed.
__global__ __launch_bounds__(256) void k_fused1(const float* __restrict__ x,
                                                const float* __restrict__ W1,
                                                unsigned int* __restrict__ Yq,
                                                float S, int N, int rowsTot, int gG,
                                                const int* __restrict__ edst, int* __restrict__ deg, int E,
                                                const int* __restrict__ pcol, int* __restrict__ ccnt, int P,
                                                const float* __restrict__ W2, const float* __restrict__ W3,
                                                unsigned short* __restrict__ Wt) {
    __shared__ float sOut[4][16 * 68];
    int tid = threadIdx.x;
    if ((int)blockIdx.x < gG) {
        int w = tid >> 6, lane = tid & 63;
        float* so = &sOut[w][0];
        int cc = lane & 15;
        int kg = (lane >> 4) * 8;
        int cr = (lane >> 4) * 4;
        int r0w = blockIdx.x * 64 + w * 16;
        int rA = r0w + (lane & 15);
        // A fragments: fp32 x -> bf16, row = n*8+b layout
        ABFrag a[2];
#pragma unroll
        for (int h = 0; h < 2; ++h) {
            if (rA < rowsTot) {
                int n = rA >> 3, b = rA & 7;
                const float* p = &x[((size_t)b * N + n) * 64 + h * 32 + kg];
                float4 v0 = *(const float4*)p;
                float4 v1 = *(const float4*)(p + 4);
                a[h].u[0] = f2bf(v0.x); a[h].u[1] = f2bf(v0.y);
                a[h].u[2] = f2bf(v0.z); a[h].u[3] = f2bf(v0.w);
                a[h].u[4] = f2bf(v1.x); a[h].u[5] = f2bf(v1.y);
                a[h].u[6] = f2bf(v1.z); a[h].u[7] = f2bf(v1.w);
            } else {
#pragma unroll
                for (int j = 0; j < 8; ++j) a[h].u[j] = 0;
            }
        }
        f32x4 acc[4] = {f32x4{}, f32x4{}, f32x4{}, f32x4{}};
        // B fragments straight from L2-hot W1 (16KB), converted in-regs:
        // lane j-th elem = W1[(k0+kg+j)*64 + c*16+cc]; 16-lane group reads
        // consecutive floats -> coalesced 64B.
#pragma unroll
        for (int h = 0; h < 2; ++h) {
#pragma unroll
            for (int c = 0; c < 4; ++c) {
                ABFrag b;
#pragma unroll
                for (int j = 0; j < 8; ++j)
                    b.u[j] = f2bf(W1[(size_t)(h * 32 + kg + j) * 64 + c * 16 + cc]);
                acc[c] = __builtin_amdgcn_mfma_f32_16x16x32_bf16(a[h].s, b.s, acc[c], 0, 0, 0);
            }
        }
#pragma unroll
        for (int c = 0; c < 4; ++c) {
            so[(cr + 0) * 68 + c * 16 + cc] = acc[c][0];
            so[(cr + 1) * 68 + c * 16 + cc] = acc[c][1];
            so[(cr + 2) * 68 + c * 16 + cc] = acc[c][2];
            so[(cr + 3) * 68 + c * 16 + cc] = acc[c][3];
        }
        __syncthreads();
#pragma unroll
        for (int i = 0; i < 4; ++i) {
            int idx = lane + i * 64;
            int row = idx >> 4, ci = idx & 15;
            int grow = r0w + row;
            if (grow < rowsTot) {
                float4 v = *(const float4*)&so[row * 68 + ci * 4];
                Yq[(size_t)grow * 16 + ci] =
                    enc4(v.x * S, v.y * S, v.z * S, v.w * S);
            }
        }
    } else {
        int cb = blockIdx.x - gG;
        int nCB = gridDim.x - gG;
        int gth = cb * 256 + tid;
        int GT = nCB * 256;
        for (int e = gth; e < E; e += GT) atomicAdd(&deg[edst[e]], 1);
        for (int p = gth; p < P; p += GT) atomicAdd(&ccnt[pcol[p]], 1);
        for (int i = gth; i < 2 * 4096; i += GT) {
            int l = i >> 12, r = i & 4095;
            int k = r >> 6, c = r & 63;
            const float* W = (l == 0) ? W2 : W3;
            Wt[(l << 12) + c * 64 + k] = f2bf(W[r]);
        }
    }
}

// ---------------- remaining preprocessing (proven R2) ----------------

__global__ __launch_bounds__(256) void k_pre_scan(const int* __restrict__ deg, int* __restrict__ rowoff, int N,
                                                  const int* __restrict__ ccnt, int* __restrict__ coff, int NC,
                                                  float* __restrict__ dinv) {
    __shared__ int part[256];
    int t = threadIdx.x;
    int gth = blockIdx.x * blockDim.x + t;
    int GT = gridDim.x * blockDim.x;
    for (int i = gth; i < N; i += GT) dinv[i] = rsqrtf((float)(deg[i] + 1));

    const int* cnt = nullptr; int* off = nullptr; int n = 0;
    if (blockIdx.x == 0)      { cnt = deg;  off = rowoff; n = N; }
    else if (blockIdx.x == 1) { cnt = ccnt; off = coff;   n = NC; }
    else return;

    int CH = (n + 255) >> 8;
    int lo = min(t * CH, n), hi = min(lo + CH, n);
    int sum = 0;
    for (int i = lo; i < hi; ++i) sum += cnt[i];
    part[t] = sum;
    __syncthreads();
    for (int o = 1; o < 256; o <<= 1) {
        int v = (t >= o) ? part[t - o] : 0;
        __syncthreads();
        part[t] += v;
        __syncthreads();
    }
    int run = (t == 0) ? 0 : part[t - 1];
    for (int i = lo; i < hi; ++i) { off[i] = run; run += cnt[i]; }
    if (t == 255) off[n] = run;
}

__global__ __launch_bounds__(256) void k_pre_scatter(const int* __restrict__ esrc, const int* __restrict__ edst,
                                                     const float* __restrict__ dinv, const int* __restrict__ rowoff,
                                                     int* __restrict__ fill, int* __restrict__ ssrc,
                                                     float* __restrict__ snorm, int E,
                                                     const int* __restrict__ prow, const int* __restrict__ pcol,
                                                     const int* __restrict__ coff, int* __restrict__ cfill,
                                                     int* __restrict__ crow, int P) {
    int gth = blockIdx.x * blockDim.x + threadIdx.x;
    int GT = gridDim.x * blockDim.x;
    for (int e = gth; e < E; e += GT) {
        int s = esrc[e], d = edst[e];
        int pos = rowoff[d] + atomicAdd(&fill[d], 1);
        ssrc[pos]  = s;
        snorm[pos] = dinv[s] * dinv[d];
    }
    for (int p = gth; p < P; p += GT) {
        int c = pcol[p];
        int pos = coff[c] + atomicAdd(&cfill[c], 1);
        crow[pos] = prow[p];
    }
}

// ---------------- aggregation (proven R2) ----------------

template<int LAYER, bool STORE>
__global__ __launch_bounds__(256) void k_agg(const uint2* __restrict__ Y,
                                             const int* __restrict__ rowoff,
                                             const int* __restrict__ ssrc,
                                             const float* __restrict__ snorm,
                                             const float* __restrict__ dinv,
                                             const float* __restrict__ bias,
                                             const float* __restrict__ fcW,
                                             uint4* __restrict__ O,
                                             float* __restrict__ sArr,
                                             float invS, int N) {
    int n = blockIdx.x * 4 + (threadIdx.x >> 6);
    if (n >= N) return;
    int lane = threadIdx.x & 63;
    int hb = (lane & 7) * 8;
    float bv[8], wv[8];
#pragma unroll
    for (int k = 0; k < 8; ++k) { bv[k] = bias[hb + k]; wv[k] = fcW[3 * (hb + k) + LAYER]; }

    float dn = dinv[n];
    float w0 = dn * dn;
    float acc[8], f[8];
    dec8(Y[(size_t)n * 64 + lane], f);
#pragma unroll
    for (int k = 0; k < 8; ++k) acc[k] = w0 * f[k];

    int beg = rowoff[n], end = rowoff[n + 1];
    int i = beg;
    for (; i + 7 < end; i += 8) {
        int   sI[8];
        float wI[8];
        uint2 g[8];
#pragma unroll
        for (int u = 0; u < 8; ++u) { sI[u] = ssrc[i + u]; wI[u] = snorm[i + u]; }
#pragma unroll
        for (int u = 0; u < 8; ++u) g[u] = Y[(size_t)sI[u] * 64 + lane];
#pragma unroll
        for (int u = 0; u < 8; ++u) {
            dec8(g[u], f);
#pragma unroll
            for (int k = 0; k < 8; ++k) acc[k] = fmaf(wI[u], f[k], acc[k]);
        }
    }
    for (; i < end; ++i) {
        int s = ssrc[i];
        float w = snorm[i];
        dec8(Y[(size_t)s * 64 + lane], f);
#pragma unroll
        for (int k = 0; k < 8; ++k) acc[k] = fmaf(w, f[k], acc[k]);
    }

    float sv = 0.f;
#pragma unroll
    for (int k = 0; k < 8; ++k) {
        float o = fmaxf(fmaf(acc[k], invS, bv[k]), 0.f);
        acc[k] = o;
        sv = fmaf(o, wv[k], sv);
    }
    if (STORE) {
        uint4 o;
        o.x = (unsigned int)f2bf(acc[0]) | ((unsigned int)f2bf(acc[1]) << 16);
        o.y = (unsigned int)f2bf(acc[2]) | ((unsigned int)f2bf(acc[3]) << 16);
        o.z = (unsigned int)f2bf(acc[4]) | ((unsigned int)f2bf(acc[5]) << 16);
        o.w = (unsigned int)f2bf(acc[6]) | ((unsigned int)f2bf(acc[7]) << 16);
        O[(size_t)n * 64 + lane] = o;
    }
    sv += __shfl_down(sv, 4, 64);
    sv += __shfl_down(sv, 2, 64);
    sv += __shfl_down(sv, 1, 64);
    if ((lane & 7) == 0) {
        int b = lane >> 3;
        float* sp = sArr + (size_t)n * 8 + b;
        if (LAYER == 0) *sp = sv;
        else            *sp += sv;
    }
}

// ---------------- fused pooling + l1 + head ----------------
// Block (gx, b): pools its own CHUNK columns for batch b (block-local; no
// cross-block dep -> k_poolg dispatch and hpoolT round-trip removed), then
// l1 partial, then last-done block runs l2 + log_softmax.
__global__ __launch_bounds__(128) void k_l1pool(const float* __restrict__ sArr,
                                                const int* __restrict__ coff,
                                                const int* __restrict__ crow,
                                                const float* __restrict__ fcb,
                                                const float* __restrict__ l1W,
                                                float* __restrict__ hpre,
                                                int* __restrict__ done,
                                                const float* __restrict__ l1b,
                                                const float* __restrict__ l2W,
                                                const float* __restrict__ l2b,
                                                float* __restrict__ out,
                                                int NC, int HFC, int bs, int NCLS,
                                                int CHUNK, int nBlocks) {
    __shared__ float hl[64];
    int b = blockIdx.y;
    int c0 = blockIdx.x * CHUNK;
    int j = threadIdx.x;
    int cend = min(c0 + CHUNK, NC);
    // ---- pool: 16 lanes per column, 8 columns in parallel (2 waves x 4) ----
    {
        int w = j >> 6, lane = j & 63, q = lane >> 4, s = lane & 15;
        float fcb0 = fcb[0];
        for (int c = c0 + w * 4 + q; c < cend; c += 8) {
            int beg = coff[c], end = coff[c + 1];
            float acc = 0.f;
            for (int i = beg + s; i < end; i += 16)
                acc += sArr[(size_t)crow[i] * 8 + b];
            acc += __shfl_down(acc, 8, 16);
            acc += __shfl_down(acc, 4, 16);
            acc += __shfl_down(acc, 2, 16);
            acc += __shfl_down(acc, 1, 16);
            if (s == 0)
                hl[c - c0] = acc / fmaxf((float)(end - beg), 1.f) + fcb0;
        }
    }
    __syncthreads();
    float acc = 0.f;
    for (int c = c0; c < cend; ++c) acc = fmaf(hl[c - c0], l1W[(size_t)c * HFC + j], acc);
    atomicAdd(&hpre[(size_t)b * HFC + j], acc);

    // ---- last-done election ----
    __threadfence();
    __syncthreads();
    __shared__ int amLast;
    if (j == 0) amLast = (atomicAdd(done, 1) == nBlocks - 1);
    __syncthreads();
    if (!amLast) return;
    __threadfence();

    // ---- final: relu(l1) -> l2 -> log_softmax ----
    __shared__ float sZ[64];
    int g = j >> 3, l8 = j & 7;
    int nout = bs * NCLS;
    float v = 0.f;
    int b2 = g / NCLS, k2 = g - b2 * NCLS;
    if (g < nout) {
        for (int jj = l8; jj < HFC; jj += 8) {
            float h = fmaxf(hpre[(size_t)b2 * HFC + jj] + l1b[jj], 0.f);
            v = fmaf(h, l2W[(size_t)jj * NCLS + k2], v);
        }
    }
    v += __shfl_down(v, 4, 8);
    v += __shfl_down(v, 2, 8);
    v += __shfl_down(v, 1, 8);
    if (l8 == 0 && g < nout) sZ[g] = v + l2b[k2];
    __syncthreads();
    if (j < bs) {
        float m = -1e30f;
        for (int c = 0; c < NCLS; ++c) m = fmaxf(m, sZ[j * NCLS + c]);
        float s = 0.f;
        for (int c = 0; c < NCLS; ++c) s += expf(sZ[j * NCLS + c] - m);
        float lse = m + logf(s);
        for (int c = 0; c < NCLS; ++c) out[j * NCLS + c] = sZ[j * NCLS + c] - lse;
    }
}

// ---------------- launcher ----------------

extern "C" void kernel_launch(void* const* d_in, const int* in_sizes, int n_in,
                              void* d_out, int out_size, void* d_ws, size_t ws_size,
                              hipStream_t stream) {
    const float* x   = (const float*)d_in[0];
    const int* eidx  = (const int*)d_in[2];
    const int* prow  = (const int*)d_in[3];
    const int* pcol  = (const int*)d_in[4];
    const float* W1  = (const float*)d_in[5];
    const float* b1  = (const float*)d_in[6];
    const float* W2  = (const float*)d_in[7];
    const float* b2  = (const float*)d_in[8];
    const float* W3  = (const float*)d_in[9];
    const float* b3  = (const float*)d_in[10];
    const float* fcW = (const float*)d_in[11];
    const float* fcb = (const float*)d_in[12];
    const float* l1W = (const float*)d_in[13];
    const float* l1b = (const float*)d_in[14];
    const float* l2W = (const float*)d_in[15];
    const float* l2b = (const float*)d_in[16];
    float* out = (float*)d_out;

    const int bs   = in_sizes[1];                 // 8
    const int E    = in_sizes[2] / 2;
    const int P    = in_sizes[3];
    const int N    = in_sizes[0] / (bs * HID);
    const int HFC  = in_sizes[14];                // 128
    const int NC   = in_sizes[13] / HFC;          // 1000
    const int NCLS = in_sizes[15] / HFC;          // 2
    const int rows = N * bs;

    const int* esrc = eidx;
    const int* edst = eidx + E;

    size_t off = 0;
    auto alloc = [&](size_t bytes) -> void* {
        void* r = (char*)d_ws + off;
        off += (bytes + 255) & ~(size_t)255;
        return r;
    };
    // ---- zero region (one memset) ----
    char* zbase   = (char*)d_ws;
    int*   deg    = (int*)  alloc((size_t)N * 4);
    int*   fill   = (int*)  alloc((size_t)N * 4);
    int*   ccnt   = (int*)  alloc((size_t)NC * 4);
    int*   cfill  = (int*)  alloc((size_t)NC * 4);
    float* hpre   = (float*)alloc((size_t)bs * HFC * 4);
    int*   done   = (int*)  alloc(4);
    size_t zspan  = off;
    // ---- rest ----
    float* dinv   = (float*)alloc((size_t)N * 4);
    int*   rowoff = (int*)  alloc(((size_t)N + 1) * 4);
    int*   coff   = (int*)  alloc(((size_t)NC + 1) * 4);
    int*   crow   = (int*)  alloc((size_t)P * 4);
    int*   ssrc   = (int*)  alloc((size_t)E * 4);
    float* snorm  = (float*)alloc((size_t)E * 4);
    unsigned int* Yq   = (unsigned int*)alloc((size_t)rows * HID);
    unsigned short* X1 = (unsigned short*)alloc((size_t)rows * HID * 2);
    unsigned short* X2 = (unsigned short*)alloc((size_t)rows * HID * 2);
    float* sArr   = (float*)alloc((size_t)rows * 4);
    unsigned short* Wt = (unsigned short*)alloc((size_t)2 * 64 * 64 * 2);

    hipMemsetAsync(zbase, 0, zspan, stream);

    const float S1 = 1.f,  iS1 = 1.f;
    const float S2 = 16.f, iS2 = 1.f / 16.f;
    const float S3 = 128.f, iS3 = 1.f / 128.f;

    int gG = (rows + 63) / 64;
    int gA = (N + 3) / 4;
    int gPre = 512;

    // dispatch 1: GEMM1 (x, W1-in-regs) || degree/col counts + Wt(W2,W3)
    k_fused1<<<gG + gPre, 256, 0, stream>>>(x, W1, Yq, S1, N, rows, gG,
                                            edst, deg, E, pcol, ccnt, P, W2, W3, Wt);
    k_pre_scan<<<64, 256, 0, stream>>>(deg, rowoff, N, ccnt, coff, NC, dinv);
    k_pre_scatter<<<gPre, 256, 0, stream>>>(esrc, edst, dinv, rowoff, fill, ssrc, snorm, E,
                                            prow, pcol, coff, cfill, crow, P);

    k_agg<0, true><<<gA, 256, 0, stream>>>((const uint2*)Yq, rowoff, ssrc, snorm, dinv, b1, fcW, (uint4*)X1, sArr, iS1, N);
    k_gemm_mfma<0><<<gG, 256, 0, stream>>>(X1, Wt, Yq, S2, rows);
    k_agg<1, true><<<gA, 256, 0, stream>>>((const uint2*)Yq, rowoff, ssrc, snorm, dinv, b2, fcW, (uint4*)X2, sArr, iS2, N);
    k_gemm_mfma<0><<<gG, 256, 0, stream>>>(X2, Wt + 4096, Yq, S3, rows);
    k_agg<2, false><<<gA, 256, 0, stream>>>((const uint2*)Yq, rowoff, ssrc, snorm, dinv, b3, fcW, nullptr, sArr, iS3, N);

    const int CHUNK = 40;
    dim3 gL1((NC + CHUNK - 1) / CHUNK, bs);
    int nBlocks = gL1.x * gL1.y;   // 200
    k_l1pool<<<gL1, 128, 0, stream>>>(sArr, coff, crow, fcb, l1W, hpre, done,
                                      l1b, l2W, l2b, out, NC, HFC, bs, NCLS, CHUNK, nBlocks);
}

// Round 5
// 355.467 us; speedup vs baseline: 2.7704x; 1.0354x over previous
//
#include <hip/hip_runtime.h>
#include <hip/hip_bf16.h>
#include <hip/hip_fp16.h>
#include <math.h>

#define HID 64

#if defined(__has_builtin)
#if __has_builtin(__builtin_amdgcn_cvt_pk_f32_fp8) && __has_builtin(__builtin_amdgcn_cvt_pk_fp8_f32)
#define HWFP8 1
#endif
#endif

typedef float vfloat2 __attribute__((ext_vector_type(2)));
typedef __attribute__((ext_vector_type(8))) short short8_t;   // 8 bf16 (4 VGPRs)
typedef __attribute__((ext_vector_type(4))) float f32x4;

union ABFrag { short8_t s; unsigned short u[8]; };

// ---------------- helpers ----------------

__device__ __forceinline__ unsigned short f2bf(float x) {
    unsigned int u = __float_as_uint(x);
    unsigned int r = u + 0x7fffu + ((u >> 16) & 1u);   // RNE
    return (unsigned short)(r >> 16);
}

#ifndef HWFP8
__device__ __forceinline__ unsigned int enc8_sw(float a) {
    unsigned short hb = __half_as_ushort(__float2half(a));
    unsigned int r = (unsigned int)hb + 0x7fu + ((hb >> 8) & 1u);
    return (r >> 8) & 0xffu;
}
__device__ __forceinline__ float dec8_sw(unsigned int b) {
    return __half2float(__ushort_as_half((unsigned short)(b << 8)));
}
#endif

__device__ __forceinline__ unsigned int enc4(float a, float b, float c, float d) {
#ifdef HWFP8
    int r = __builtin_amdgcn_cvt_pk_fp8_f32(a, b, 0, false);
    r = __builtin_amdgcn_cvt_pk_fp8_f32(c, d, r, true);
    return (unsigned int)r;
#else
    return enc8_sw(a) | (enc8_sw(b) << 8) | (enc8_sw(c) << 16) | (enc8_sw(d) << 24);
#endif
}

__device__ __forceinline__ void dec4(unsigned int w, float* f) {
#ifdef HWFP8
    vfloat2 a = __builtin_amdgcn_cvt_pk_f32_fp8((int)w, false);
    vfloat2 b = __builtin_amdgcn_cvt_pk_f32_fp8((int)w, true);
    f[0] = a.x; f[1] = a.y; f[2] = b.x; f[3] = b.y;
#else
    f[0] = dec8_sw(w & 0xffu); f[1] = dec8_sw((w >> 8) & 0xffu);
    f[2] = dec8_sw((w >> 16) & 0xffu); f[3] = dec8_sw(w >> 24);
#endif
}

__device__ __forceinline__ void dec8(uint2 g, float* f) {
    dec4(g.x, f);
    dec4(g.y, f + 4);
}

// ---------------- GEMM epilogue (per-wave LDS transpose + fp8 pack) ----------------
__device__ __forceinline__ void gemm_epilogue(float* so, const f32x4* acc,
                                              unsigned int* Yq, float S,
                                              int r0w, int rowsTot, int lane) {
    int cc = lane & 15;
    int cr = (lane >> 4) * 4;
#pragma unroll
    for (int c = 0; c < 4; ++c) {
        so[(cr + 0) * 68 + c * 16 + cc] = acc[c][0];
        so[(cr + 1) * 68 + c * 16 + cc] = acc[c][1];
        so[(cr + 2) * 68 + c * 16 + cc] = acc[c][2];
        so[(cr + 3) * 68 + c * 16 + cc] = acc[c][3];
    }
    __syncthreads();
#pragma unroll
    for (int i = 0; i < 4; ++i) {
        int idx = lane + i * 64;
        int row = idx >> 4, ci = idx & 15;
        int grow = r0w + row;
        if (grow < rowsTot) {
            float4 v = *(const float4*)&so[row * 68 + ci * 4];
            Yq[(size_t)grow * 16 + ci] = enc4(v.x * S, v.y * S, v.z * S, v.w * S);
        }
    }
}

// ---------------- GEMM layers 2/3: 128 rows/block (2 tiles), B-frags in regs ----------------
// Y[row, h] = (sum_k X[row, k] * W[k, h]) * S, Y fp8. X bf16 [row, k].
// Fragment layouts (gfx950, m89-verified): A row=lane&15, k=(lane>>4)*8+j;
// B col=lane&15, same k; D col=lane&15, row=(lane>>4)*4+reg.
template<int DUMMY>
__global__ __launch_bounds__(256) void k_gemm_mfma(const unsigned short* __restrict__ Xh,
                                                   const unsigned short* __restrict__ Wt,
                                                   unsigned int* __restrict__ Yq,
                                                   float S, int rowsTot) {
    __shared__ float sOut[4][16 * 68];
    int tid = threadIdx.x;
    int w = tid >> 6, lane = tid & 63;
    int cc = lane & 15, kg = (lane >> 4) * 8;
    float* so = &sOut[w][0];

    // B fragments once (8 x 16B vector loads from L2-hot 8KB Wt)
    ABFrag bf[2][4];
#pragma unroll
    for (int h = 0; h < 2; ++h)
#pragma unroll
        for (int c = 0; c < 4; ++c)
            bf[h][c].s = *(const short8_t*)&Wt[(size_t)(c * 16 + cc) * 64 + h * 32 + kg];

    int base = blockIdx.x * 128;
    // prefetch tile 0 A
    ABFrag a[2];
    {
        int rA = base + w * 16 + (lane & 15);
#pragma unroll
        for (int h = 0; h < 2; ++h) {
            if (rA < rowsTot) a[h].s = *(const short8_t*)&Xh[(size_t)rA * 64 + h * 32 + kg];
            else { for (int j = 0; j < 8; ++j) a[h].u[j] = 0; }
        }
    }
#pragma unroll
    for (int t = 0; t < 2; ++t) {
        ABFrag an[2];
        if (t < 1) {
            int rA = base + 64 + w * 16 + (lane & 15);
#pragma unroll
            for (int h = 0; h < 2; ++h) {
                if (rA < rowsTot) an[h].s = *(const short8_t*)&Xh[(size_t)rA * 64 + h * 32 + kg];
                else { for (int j = 0; j < 8; ++j) an[h].u[j] = 0; }
            }
        }
        f32x4 acc[4] = {f32x4{}, f32x4{}, f32x4{}, f32x4{}};
#pragma unroll
        for (int h = 0; h < 2; ++h)
#pragma unroll
            for (int c = 0; c < 4; ++c)
                acc[c] = __builtin_amdgcn_mfma_f32_16x16x32_bf16(a[h].s, bf[h][c].s, acc[c], 0, 0, 0);
        gemm_epilogue(so, acc, Yq, S, base + t * 64 + w * 16, rowsTot, lane);
        if (t < 1) { a[0] = an[0]; a[1] = an[1]; __syncthreads(); }
    }
}

// ---------------- fused dispatch 1: GEMM1 (x fp32, W1 via LDS) || pre-count ----------------
// Blocks [0, gGf): layer-1 GEMM, 128 rows each; W1 staged coalesced into LDS
// as bf16 [c][k] then read as ds_read_b128 fragments (fixes R4's 64-scalar-load
// regression). Blocks [gGf, ...): degree/col counts + Wt conversion (W2,W3).
__global__ __launch_bounds__(256) void k_fused1(const float* __restrict__ x,
                                                const float* __restrict__ W1,
                                                unsigned int* __restrict__ Yq,
                                                float S, int N, int rowsTot, int gGf,
                                                const int* __restrict__ edst, int* __restrict__ deg, int E,
                                                const int* __restrict__ pcol, int* __restrict__ ccnt, int P,
                                                const float* __restrict__ W2, const float* __restrict__ W3,
                                                unsigned short* __restrict__ Wt) {
    __shared__ float sOut[4][16 * 68];
    __shared__ unsigned short sW[4096];   // W1 bf16, [c][k]
    int tid = threadIdx.x;
    if ((int)blockIdx.x < gGf) {
        int w = tid >> 6, lane = tid & 63;
        int cc = lane & 15, kg = (lane >> 4) * 8;
        float* so = &sOut[w][0];
        // stage W1 -> LDS (coalesced global read; one-time transposed write)
#pragma unroll
        for (int i = 0; i < 16; ++i) {
            int idx = i * 256 + tid;
            int k = idx >> 6, c = idx & 63;
            sW[c * 64 + k] = f2bf(W1[idx]);
        }
        __syncthreads();
        ABFrag bf[2][4];
#pragma unroll
        for (int h = 0; h < 2; ++h)
#pragma unroll
            for (int c = 0; c < 4; ++c)
                bf[h][c].s = *(const short8_t*)&sW[(c * 16 + cc) * 64 + h * 32 + kg];

        int base = blockIdx.x * 128;
        ABFrag a[2];
        auto loadA = [&](int rA, ABFrag* dst) {
#pragma unroll
            for (int h = 0; h < 2; ++h) {
                if (rA < rowsTot) {
                    int n = rA >> 3, b = rA & 7;
                    const float* p = &x[((size_t)b * N + n) * 64 + h * 32 + kg];
                    float4 v0 = *(const float4*)p;
                    float4 v1 = *(const float4*)(p + 4);
                    dst[h].u[0] = f2bf(v0.x); dst[h].u[1] = f2bf(v0.y);
                    dst[h].u[2] = f2bf(v0.z); dst[h].u[3] = f2bf(v0.w);
                    dst[h].u[4] = f2bf(v1.x); dst[h].u[5] = f2bf(v1.y);
                    dst[h].u[6] = f2bf(v1.z); dst[h].u[7] = f2bf(v1.w);
                } else {
#pragma unroll
                    for (int j = 0; j < 8; ++j) dst[h].u[j] = 0;
                }
            }
        };
        loadA(base + w * 16 + (lane & 15), a);
#pragma unroll
        for (int t = 0; t < 2; ++t) {
            ABFrag an[2];
            if (t < 1) loadA(base + 64 + w * 16 + (lane & 15), an);
            f32x4 acc[4] = {f32x4{}, f32x4{}, f32x4{}, f32x4{}};
#pragma unroll
            for (int h = 0; h < 2; ++h)
#pragma unroll
                for (int c = 0; c < 4; ++c)
                    acc[c] = __builtin_amdgcn_mfma_f32_16x16x32_bf16(a[h].s, bf[h][c].s, acc[c], 0, 0, 0);
            gemm_epilogue(so, acc, Yq, S, base + t * 64 + w * 16, rowsTot, lane);
            if (t < 1) { a[0] = an[0]; a[1] = an[1]; __syncthreads(); }
        }
    } else {
        int cb = blockIdx.x - gGf;
        int nCB = gridDim.x - gGf;
        int gth = cb * 256 + tid;
        int GT = nCB * 256;
        for (int e = gth; e < E; e += GT) atomicAdd(&deg[edst[e]], 1);
        for (int p = gth; p < P; p += GT) atomicAdd(&ccnt[pcol[p]], 1);
        for (int i = gth; i < 2 * 4096; i += GT) {
            int l = i >> 12, r = i & 4095;
            int k = r >> 6, c = r & 63;
            const float* W = (l == 0) ? W2 : W3;
            Wt[(l << 12) + c * 64 + k] = f2bf(W[r]);
        }
    }
}

// ---------------- remaining preprocessing (proven R2) ----------------

__global__ __launch_bounds__(256) void k_pre_scan(const int* __restrict__ deg, int* __restrict__ rowoff, int N,
                                                  const int* __restrict__ ccnt, int* __restrict__ coff, int NC,
                                                  float* __restrict__ dinv) {
    __shared__ int part[256];
    int t = threadIdx.x;
    int gth = blockIdx.x * blockDim.x + t;
    int GT = gridDim.x * blockDim.x;
    for (int i = gth; i < N; i += GT) dinv[i] = rsqrtf((float)(deg[i] + 1));

    const int* cnt = nullptr; int* off = nullptr; int n = 0;
    if (blockIdx.x == 0)      { cnt = deg;  off = rowoff; n = N; }
    else if (blockIdx.x == 1) { cnt = ccnt; off = coff;   n = NC; }
    else return;

    int CH = (n + 255) >> 8;
    int lo = min(t * CH, n), hi = min(lo + CH, n);
    int sum = 0;
    for (int i = lo; i < hi; ++i) sum += cnt[i];
    part[t] = sum;
    __syncthreads();
    for (int o = 1; o < 256; o <<= 1) {
        int v = (t >= o) ? part[t - o] : 0;
        __syncthreads();
        part[t] += v;
        __syncthreads();
    }
    int run = (t == 0) ? 0 : part[t - 1];
    for (int i = lo; i < hi; ++i) { off[i] = run; run += cnt[i]; }
    if (t == 255) off[n] = run;
}

__global__ __launch_bounds__(256) void k_pre_scatter(const int* __restrict__ esrc, const int* __restrict__ edst,
                                                     const float* __restrict__ dinv, const int* __restrict__ rowoff,
                                                     int* __restrict__ fill, int* __restrict__ ssrc,
                                                     float* __restrict__ snorm, int E,
                                                     const int* __restrict__ prow, const int* __restrict__ pcol,
                                                     const int* __restrict__ coff, int* __restrict__ cfill,
                                                     int* __restrict__ crow, int P) {
    int gth = blockIdx.x * blockDim.x + threadIdx.x;
    int GT = gridDim.x * blockDim.x;
    for (int e = gth; e < E; e += GT) {
        int s = esrc[e], d = edst[e];
        int pos = rowoff[d] + atomicAdd(&fill[d], 1);
        ssrc[pos]  = s;
        snorm[pos] = dinv[s] * dinv[d];
    }
    for (int p = gth; p < P; p += GT) {
        int c = pcol[p];
        int pos = coff[c] + atomicAdd(&cfill[c], 1);
        crow[pos] = prow[p];
    }
}

// ---------------- aggregation (proven R2) ----------------

template<int LAYER, bool STORE>
__global__ __launch_bounds__(256) void k_agg(const uint2* __restrict__ Y,
                                             const int* __restrict__ rowoff,
                                             const int* __restrict__ ssrc,
                                             const float* __restrict__ snorm,
                                             const float* __restrict__ dinv,
                                             const float* __restrict__ bias,
                                             const float* __restrict__ fcW,
                                             uint4* __restrict__ O,
                                             float* __restrict__ sArr,
                                             float invS, int N) {
    int n = blockIdx.x * 4 + (threadIdx.x >> 6);
    if (n >= N) return;
    int lane = threadIdx.x & 63;
    int hb = (lane & 7) * 8;
    float bv[8], wv[8];
#pragma unroll
    for (int k = 0; k < 8; ++k) { bv[k] = bias[hb + k]; wv[k] = fcW[3 * (hb + k) + LAYER]; }

    float dn = dinv[n];
    float w0 = dn * dn;
    float acc[8], f[8];
    dec8(Y[(size_t)n * 64 + lane], f);
#pragma unroll
    for (int k = 0; k < 8; ++k) acc[k] = w0 * f[k];

    int beg = rowoff[n], end = rowoff[n + 1];
    int i = beg;
    for (; i + 7 < end; i += 8) {
        int   sI[8];
        float wI[8];
        uint2 g[8];
#pragma unroll
        for (int u = 0; u < 8; ++u) { sI[u] = ssrc[i + u]; wI[u] = snorm[i + u]; }
#pragma unroll
        for (int u = 0; u < 8; ++u) g[u] = Y[(size_t)sI[u] * 64 + lane];
#pragma unroll
        for (int u = 0; u < 8; ++u) {
            dec8(g[u], f);
#pragma unroll
            for (int k = 0; k < 8; ++k) acc[k] = fmaf(wI[u], f[k], acc[k]);
        }
    }
    for (; i < end; ++i) {
        int s = ssrc[i];
        float w = snorm[i];
        dec8(Y[(size_t)s * 64 + lane], f);
#pragma unroll
        for (int k = 0; k < 8; ++k) acc[k] = fmaf(w, f[k], acc[k]);
    }

    float sv = 0.f;
#pragma unroll
    for (int k = 0; k < 8; ++k) {
        float o = fmaxf(fmaf(acc[k], invS, bv[k]), 0.f);
        acc[k] = o;
        sv = fmaf(o, wv[k], sv);
    }
    if (STORE) {
        uint4 o;
        o.x = (unsigned int)f2bf(acc[0]) | ((unsigned int)f2bf(acc[1]) << 16);
        o.y = (unsigned int)f2bf(acc[2]) | ((unsigned int)f2bf(acc[3]) << 16);
        o.z = (unsigned int)f2bf(acc[4]) | ((unsigned int)f2bf(acc[5]) << 16);
        o.w = (unsigned int)f2bf(acc[6]) | ((unsigned int)f2bf(acc[7]) << 16);
        O[(size_t)n * 64 + lane] = o;
    }
    sv += __shfl_down(sv, 4, 64);
    sv += __shfl_down(sv, 2, 64);
    sv += __shfl_down(sv, 1, 64);
    if ((lane & 7) == 0) {
        int b = lane >> 3;
        float* sp = sArr + (size_t)n * 8 + b;
        if (LAYER == 0) *sp = sv;
        else            *sp += sv;
    }
}

// ---------------- fused pooling + l1 + head (proven R4) ----------------

__global__ __launch_bounds__(128) void k_l1pool(const float* __restrict__ sArr,
                                                const int* __restrict__ coff,
                                                const int* __restrict__ crow,
                                                const float* __restrict__ fcb,
                                                const float* __restrict__ l1W,
                                                float* __restrict__ hpre,
                                                int* __restrict__ done,
                                                const float* __restrict__ l1b,
                                                const float* __restrict__ l2W,
                                                const float* __restrict__ l2b,
                                                float* __restrict__ out,
                                                int NC, int HFC, int bs, int NCLS,
                                                int CHUNK, int nBlocks) {
    __shared__ float hl[64];
    int b = blockIdx.y;
    int c0 = blockIdx.x * CHUNK;
    int j = threadIdx.x;
    int cend = min(c0 + CHUNK, NC);
    {
        int w = j >> 6, lane = j & 63, q = lane >> 4, s = lane & 15;
        float fcb0 = fcb[0];
        for (int c = c0 + w * 4 + q; c < cend; c += 8) {
            int beg = coff[c], end = coff[c + 1];
            float acc = 0.f;
            for (int i = beg + s; i < end; i += 16)
                acc += sArr[(size_t)crow[i] * 8 + b];
            acc += __shfl_down(acc, 8, 16);
            acc += __shfl_down(acc, 4, 16);
            acc += __shfl_down(acc, 2, 16);
            acc += __shfl_down(acc, 1, 16);
            if (s == 0)
                hl[c - c0] = acc / fmaxf((float)(end - beg), 1.f) + fcb0;
        }
    }
    __syncthreads();
    float acc = 0.f;
    for (int c = c0; c < cend; ++c) acc = fmaf(hl[c - c0], l1W[(size_t)c * HFC + j], acc);
    atomicAdd(&hpre[(size_t)b * HFC + j], acc);

    __threadfence();
    __syncthreads();
    __shared__ int amLast;
    if (j == 0) amLast = (atomicAdd(done, 1) == nBlocks - 1);
    __syncthreads();
    if (!amLast) return;
    __threadfence();

    __shared__ float sZ[64];
    int g = j >> 3, l8 = j & 7;
    int nout = bs * NCLS;
    float v = 0.f;
    int b2 = g / NCLS, k2 = g - b2 * NCLS;
    if (g < nout) {
        for (int jj = l8; jj < HFC; jj += 8) {
            float h = fmaxf(hpre[(size_t)b2 * HFC + jj] + l1b[jj], 0.f);
            v = fmaf(h, l2W[(size_t)jj * NCLS + k2], v);
        }
    }
    v += __shfl_down(v, 4, 8);
    v += __shfl_down(v, 2, 8);
    v += __shfl_down(v, 1, 8);
    if (l8 == 0 && g < nout) sZ[g] = v + l2b[k2];
    __syncthreads();
    if (j < bs) {
        float m = -1e30f;
        for (int c = 0; c < NCLS; ++c) m = fmaxf(m, sZ[j * NCLS + c]);
        float s = 0.f;
        for (int c = 0; c < NCLS; ++c) s += expf(sZ[j * NCLS + c] - m);
        float lse = m + logf(s);
        for (int c = 0; c < NCLS; ++c) out[j * NCLS + c] = sZ[j * NCLS + c] - lse;
    }
}

// ---------------- launcher ----------------

extern "C" void kernel_launch(void* const* d_in, const int* in_sizes, int n_in,
                              void* d_out, int out_size, void* d_ws, size_t ws_size,
                              hipStream_t stream) {
    const float* x   = (const float*)d_in[0];
    const int* eidx  = (const int*)d_in[2];
    const int* prow  = (const int*)d_in[3];
    const int* pcol  = (const int*)d_in[4];
    const float* W1  = (const float*)d_in[5];
    const float* b1  = (const float*)d_in[6];
    const float* W2  = (const float*)d_in[7];
    const float* b2  = (const float*)d_in[8];
    const float* W3  = (const float*)d_in[9];
    const float* b3  = (const float*)d_in[10];
    const float* fcW = (const float*)d_in[11];
    const float* fcb = (const float*)d_in[12];
    const float* l1W = (const float*)d_in[13];
    const float* l1b = (const float*)d_in[14];
    const float* l2W = (const float*)d_in[15];
    const float* l2b = (const float*)d_in[16];
    float* out = (float*)d_out;

    const int bs   = in_sizes[1];                 // 8
    const int E    = in_sizes[2] / 2;
    const int P    = in_sizes[3];
    const int N    = in_sizes[0] / (bs * HID);
    const int HFC  = in_sizes[14];                // 128
    const int NC   = in_sizes[13] / HFC;          // 1000
    const int NCLS = in_sizes[15] / HFC;          // 2
    const int rows = N * bs;

    const int* esrc = eidx;
    const int* edst = eidx + E;

    size_t off = 0;
    auto alloc = [&](size_t bytes) -> void* {
        void* r = (char*)d_ws + off;
        off += (bytes + 255) & ~(size_t)255;
        return r;
    };
    // ---- zero region (one memset) ----
    char* zbase   = (char*)d_ws;
    int*   deg    = (int*)  alloc((size_t)N * 4);
    int*   fill   = (int*)  alloc((size_t)N * 4);
    int*   ccnt   = (int*)  alloc((size_t)NC * 4);
    int*   cfill  = (int*)  alloc((size_t)NC * 4);
    float* hpre   = (float*)alloc((size_t)bs * HFC * 4);
    int*   done   = (int*)  alloc(4);
    size_t zspan  = off;
    // ---- rest ----
    float* dinv   = (float*)alloc((size_t)N * 4);
    int*   rowoff = (int*)  alloc(((size_t)N + 1) * 4);
    int*   coff   = (int*)  alloc(((size_t)NC + 1) * 4);
    int*   crow   = (int*)  alloc((size_t)P * 4);
    int*   ssrc   = (int*)  alloc((size_t)E * 4);
    float* snorm  = (float*)alloc((size_t)E * 4);
    unsigned int* Yq   = (unsigned int*)alloc((size_t)rows * HID);
    unsigned short* X1 = (unsigned short*)alloc((size_t)rows * HID * 2);
    unsigned short* X2 = (unsigned short*)alloc((size_t)rows * HID * 2);
    float* sArr   = (float*)alloc((size_t)rows * 4);
    unsigned short* Wt = (unsigned short*)alloc((size_t)2 * 64 * 64 * 2);

    hipMemsetAsync(zbase, 0, zspan, stream);

    const float S1 = 1.f,  iS1 = 1.f;
    const float S2 = 16.f, iS2 = 1.f / 16.f;
    const float S3 = 128.f, iS3 = 1.f / 128.f;

    int gG2 = (rows + 127) / 128;   // 946
    int gA = (N + 3) / 4;
    int gPre = 512;

    // dispatch 1: GEMM1 (x, W1-via-LDS) || degree/col counts + Wt(W2,W3)
    k_fused1<<<gG2 + gPre, 256, 0, stream>>>(x, W1, Yq, S1, N, rows, gG2,
                                             edst, deg, E, pcol, ccnt, P, W2, W3, Wt);
    k_pre_scan<<<64, 256, 0, stream>>>(deg, rowoff, N, ccnt, coff, NC, dinv);
    k_pre_scatter<<<gPre, 256, 0, stream>>>(esrc, edst, dinv, rowoff, fill, ssrc, snorm, E,
                                            prow, pcol, coff, cfill, crow, P);

    k_agg<0, true><<<gA, 256, 0, stream>>>((const uint2*)Yq, rowoff, ssrc, snorm, dinv, b1, fcW, (uint4*)X1, sArr, iS1, N);
    k_gemm_mfma<0><<<gG2, 256, 0, stream>>>(X1, Wt, Yq, S2, rows);
    k_agg<1, true><<<gA, 256, 0, stream>>>((const uint2*)Yq, rowoff, ssrc, snorm, dinv, b2, fcW, (uint4*)X2, sArr, iS2, N);
    k_gemm_mfma<0><<<gG2, 256, 0, stream>>>(X2, Wt + 4096, Yq, S3, rows);
    k_agg<2, false><<<gA, 256, 0, stream>>>((const uint2*)Yq, rowoff, ssrc, snorm, dinv, b3, fcW, nullptr, sArr, iS3, N);

    const int CHUNK = 40;
    dim3 gL1((NC + CHUNK - 1) / CHUNK, bs);
    int nBlocks = gL1.x * gL1.y;   // 200
    k_l1pool<<<gL1, 128, 0, stream>>>(sArr, coff, crow, fcb, l1W, hpre, done,
                                      l1b, l2W, l2b, out, NC, HFC, bs, NCLS, CHUNK, nBlocks);
}

// Round 6
// 350.446 us; speedup vs baseline: 2.8101x; 1.0143x over previous
//
#include <hip/hip_runtime.h>
#include <hip/hip_bf16.h>
#include <hip/hip_fp16.h>
#include <math.h>

#define HID 64

#if defined(__has_builtin)
#if __has_builtin(__builtin_amdgcn_cvt_pk_f32_fp8) && __has_builtin(__builtin_amdgcn_cvt_pk_fp8_f32)
#define HWFP8 1
#endif
#endif

typedef float vfloat2 __attribute__((ext_vector_type(2)));
typedef __attribute__((ext_vector_type(8))) short short8_t;   // 8 bf16 (4 VGPRs)
typedef __attribute__((ext_vector_type(4))) float f32x4;

union ABFrag { short8_t s; unsigned short u[8]; };

// ---------------- helpers ----------------

__device__ __forceinline__ unsigned short f2bf(float x) {
    unsigned int u = __float_as_uint(x);
    unsigned int r = u + 0x7fffu + ((u >> 16) & 1u);   // RNE
    return (unsigned short)(r >> 16);
}

#ifndef HWFP8
__device__ __forceinline__ unsigned int enc8_sw(float a) {
    unsigned short hb = __half_as_ushort(__float2half(a));
    unsigned int r = (unsigned int)hb + 0x7fu + ((hb >> 8) & 1u);
    return (r >> 8) & 0xffu;
}
__device__ __forceinline__ float dec8_sw(unsigned int b) {
    return __half2float(__ushort_as_half((unsigned short)(b << 8)));
}
#endif

__device__ __forceinline__ unsigned int enc4(float a, float b, float c, float d) {
#ifdef HWFP8
    int r = __builtin_amdgcn_cvt_pk_fp8_f32(a, b, 0, false);
    r = __builtin_amdgcn_cvt_pk_fp8_f32(c, d, r, true);
    return (unsigned int)r;
#else
    return enc8_sw(a) | (enc8_sw(b) << 8) | (enc8_sw(c) << 16) | (enc8_sw(d) << 24);
#endif
}

__device__ __forceinline__ void dec4(unsigned int w, float* f) {
#ifdef HWFP8
    vfloat2 a = __builtin_amdgcn_cvt_pk_f32_fp8((int)w, false);
    vfloat2 b = __builtin_amdgcn_cvt_pk_f32_fp8((int)w, true);
    f[0] = a.x; f[1] = a.y; f[2] = b.x; f[3] = b.y;
#else
    f[0] = dec8_sw(w & 0xffu); f[1] = dec8_sw((w >> 8) & 0xffu);
    f[2] = dec8_sw((w >> 16) & 0xffu); f[3] = dec8_sw(w >> 24);
#endif
}

__device__ __forceinline__ void dec8(uint2 g, float* f) {
    dec4(g.x, f);
    dec4(g.y, f + 4);
}

// ---------------- GEMM epilogue (per-wave LDS transpose + fp8 pack) ----------------
__device__ __forceinline__ void gemm_epilogue(float* so, const f32x4* acc,
                                              unsigned int* Yq, float S,
                                              int r0w, int rowsTot, int lane) {
    int cc = lane & 15;
    int cr = (lane >> 4) * 4;
#pragma unroll
    for (int c = 0; c < 4; ++c) {
        so[(cr + 0) * 68 + c * 16 + cc] = acc[c][0];
        so[(cr + 1) * 68 + c * 16 + cc] = acc[c][1];
        so[(cr + 2) * 68 + c * 16 + cc] = acc[c][2];
        so[(cr + 3) * 68 + c * 16 + cc] = acc[c][3];
    }
    __syncthreads();
#pragma unroll
    for (int i = 0; i < 4; ++i) {
        int idx = lane + i * 64;
        int row = idx >> 4, ci = idx & 15;
        int grow = r0w + row;
        if (grow < rowsTot) {
            float4 v = *(const float4*)&so[row * 68 + ci * 4];
            Yq[(size_t)grow * 16 + ci] = enc4(v.x * S, v.y * S, v.z * S, v.w * S);
        }
    }
}

// ---------------- fused dispatch 1: GEMM1 (x fp32, W1 via LDS) || pre-count ----------------
__global__ __launch_bounds__(256) void k_fused1(const float* __restrict__ x,
                                                const float* __restrict__ W1,
                                                unsigned int* __restrict__ Yq,
                                                float S, int N, int rowsTot, int gGf,
                                                const int* __restrict__ edst, int* __restrict__ deg, int E,
                                                const int* __restrict__ pcol, int* __restrict__ ccnt, int P,
                                                const float* __restrict__ W2, const float* __restrict__ W3,
                                                unsigned short* __restrict__ Wt) {
    __shared__ float sOut[4][16 * 68];
    __shared__ unsigned short sW[4096];   // W1 bf16, [c][k]
    int tid = threadIdx.x;
    if ((int)blockIdx.x < gGf) {
        int w = tid >> 6, lane = tid & 63;
        int cc = lane & 15, kg = (lane >> 4) * 8;
        float* so = &sOut[w][0];
#pragma unroll
        for (int i = 0; i < 16; ++i) {
            int idx = i * 256 + tid;
            int k = idx >> 6, c = idx & 63;
            sW[c * 64 + k] = f2bf(W1[idx]);
        }
        __syncthreads();
        ABFrag bf[2][4];
#pragma unroll
        for (int h = 0; h < 2; ++h)
#pragma unroll
            for (int c = 0; c < 4; ++c)
                bf[h][c].s = *(const short8_t*)&sW[(c * 16 + cc) * 64 + h * 32 + kg];

        int base = blockIdx.x * 128;
        ABFrag a[2];
        auto loadA = [&](int rA, ABFrag* dst) {
#pragma unroll
            for (int h = 0; h < 2; ++h) {
                if (rA < rowsTot) {
                    int n = rA >> 3, b = rA & 7;
                    const float* p = &x[((size_t)b * N + n) * 64 + h * 32 + kg];
                    float4 v0 = *(const float4*)p;
                    float4 v1 = *(const float4*)(p + 4);
                    dst[h].u[0] = f2bf(v0.x); dst[h].u[1] = f2bf(v0.y);
                    dst[h].u[2] = f2bf(v0.z); dst[h].u[3] = f2bf(v0.w);
                    dst[h].u[4] = f2bf(v1.x); dst[h].u[5] = f2bf(v1.y);
                    dst[h].u[6] = f2bf(v1.z); dst[h].u[7] = f2bf(v1.w);
                } else {
#pragma unroll
                    for (int j = 0; j < 8; ++j) dst[h].u[j] = 0;
                }
            }
        };
        loadA(base + w * 16 + (lane & 15), a);
#pragma unroll
        for (int t = 0; t < 2; ++t) {
            ABFrag an[2];
            if (t < 1) loadA(base + 64 + w * 16 + (lane & 15), an);
            f32x4 acc[4] = {f32x4{}, f32x4{}, f32x4{}, f32x4{}};
#pragma unroll
            for (int h = 0; h < 2; ++h)
#pragma unroll
                for (int c = 0; c < 4; ++c)
                    acc[c] = __builtin_amdgcn_mfma_f32_16x16x32_bf16(a[h].s, bf[h][c].s, acc[c], 0, 0, 0);
            gemm_epilogue(so, acc, Yq, S, base + t * 64 + w * 16, rowsTot, lane);
            if (t < 1) { a[0] = an[0]; a[1] = an[1]; __syncthreads(); }
        }
    } else {
        int cb = blockIdx.x - gGf;
        int nCB = gridDim.x - gGf;
        int gth = cb * 256 + tid;
        int GT = nCB * 256;
        for (int e = gth; e < E; e += GT) atomicAdd(&deg[edst[e]], 1);
        for (int p = gth; p < P; p += GT) atomicAdd(&ccnt[pcol[p]], 1);
        for (int i = gth; i < 2 * 4096; i += GT) {
            int l = i >> 12, r = i & 4095;
            int k = r >> 6, c = r & 63;
            const float* W = (l == 0) ? W2 : W3;
            Wt[(l << 12) + c * 64 + k] = f2bf(W[r]);
        }
    }
}

// ---------------- remaining preprocessing (proven R2) ----------------

__global__ __launch_bounds__(256) void k_pre_scan(const int* __restrict__ deg, int* __restrict__ rowoff, int N,
                                                  const int* __restrict__ ccnt, int* __restrict__ coff, int NC,
                                                  float* __restrict__ dinv) {
    __shared__ int part[256];
    int t = threadIdx.x;
    int gth = blockIdx.x * blockDim.x + t;
    int GT = gridDim.x * blockDim.x;
    for (int i = gth; i < N; i += GT) dinv[i] = rsqrtf((float)(deg[i] + 1));

    const int* cnt = nullptr; int* off = nullptr; int n = 0;
    if (blockIdx.x == 0)      { cnt = deg;  off = rowoff; n = N; }
    else if (blockIdx.x == 1) { cnt = ccnt; off = coff;   n = NC; }
    else return;

    int CH = (n + 255) >> 8;
    int lo = min(t * CH, n), hi = min(lo + CH, n);
    int sum = 0;
    for (int i = lo; i < hi; ++i) sum += cnt[i];
    part[t] = sum;
    __syncthreads();
    for (int o = 1; o < 256; o <<= 1) {
        int v = (t >= o) ? part[t - o] : 0;
        __syncthreads();
        part[t] += v;
        __syncthreads();
    }
    int run = (t == 0) ? 0 : part[t - 1];
    for (int i = lo; i < hi; ++i) { off[i] = run; run += cnt[i]; }
    if (t == 255) off[n] = run;
}

__global__ __launch_bounds__(256) void k_pre_scatter(const int* __restrict__ esrc, const int* __restrict__ edst,
                                                     const float* __restrict__ dinv, const int* __restrict__ rowoff,
                                                     int* __restrict__ fill, int* __restrict__ ssrc,
                                                     float* __restrict__ snorm, int E,
                                                     const int* __restrict__ prow, const int* __restrict__ pcol,
                                                     const int* __restrict__ coff, int* __restrict__ cfill,
                                                     int* __restrict__ crow, int P) {
    int gth = blockIdx.x * blockDim.x + threadIdx.x;
    int GT = gridDim.x * blockDim.x;
    for (int e = gth; e < E; e += GT) {
        int s = esrc[e], d = edst[e];
        int pos = rowoff[d] + atomicAdd(&fill[d], 1);
        ssrc[pos]  = s;
        snorm[pos] = dinv[s] * dinv[d];
    }
    for (int p = gth; p < P; p += GT) {
        int c = pcol[p];
        int pos = coff[c] + atomicAdd(&cfill[c], 1);
        crow[pos] = prow[p];
    }
}

// ---------------- agg core (proven R2 math; target = LDS row or global) ----------------

template<int LAYER>
__device__ __forceinline__ void agg_node(const uint2* __restrict__ Y,
                                         const int* __restrict__ rowoff,
                                         const int* __restrict__ ssrc,
                                         const float* __restrict__ snorm,
                                         const float* __restrict__ dinv,
                                         const float* bv, const float* wv,
                                         float* __restrict__ sArr,
                                         float invS, int n, int lane,
                                         float* accOut) {
    float dn = dinv[n];
    float w0 = dn * dn;
    float acc[8], f[8];
    dec8(Y[(size_t)n * 64 + lane], f);
#pragma unroll
    for (int k = 0; k < 8; ++k) acc[k] = w0 * f[k];

    int beg = rowoff[n], end = rowoff[n + 1];
    int i = beg;
    for (; i + 7 < end; i += 8) {
        int   sI[8];
        float wI[8];
        uint2 g[8];
#pragma unroll
        for (int u = 0; u < 8; ++u) { sI[u] = ssrc[i + u]; wI[u] = snorm[i + u]; }
#pragma unroll
        for (int u = 0; u < 8; ++u) g[u] = Y[(size_t)sI[u] * 64 + lane];
#pragma unroll
        for (int u = 0; u < 8; ++u) {
            dec8(g[u], f);
#pragma unroll
            for (int k = 0; k < 8; ++k) acc[k] = fmaf(wI[u], f[k], acc[k]);
        }
    }
    for (; i < end; ++i) {
        int s = ssrc[i];
        float w = snorm[i];
        dec8(Y[(size_t)s * 64 + lane], f);
#pragma unroll
        for (int k = 0; k < 8; ++k) acc[k] = fmaf(w, f[k], acc[k]);
    }

    float sv = 0.f;
#pragma unroll
    for (int k = 0; k < 8; ++k) {
        float o = fmaxf(fmaf(acc[k], invS, bv[k]), 0.f);
        accOut[k] = o;
        sv = fmaf(o, wv[k], sv);
    }
    sv += __shfl_down(sv, 4, 64);
    sv += __shfl_down(sv, 2, 64);
    sv += __shfl_down(sv, 1, 64);
    if ((lane & 7) == 0) {
        int b = lane >> 3;
        float* sp = sArr + (size_t)n * 8 + b;
        if (LAYER == 0) *sp = sv;
        else            *sp += sv;
    }
}

// ---------------- fused agg(L) + gemm(L+1): 8 nodes = 64 rows per block ----------------
// Agg writes relu'd bf16 X rows into XOR-swizzled LDS (no global X round-trip),
// then the block runs the 64-row MFMA GEMM from LDS. Yin/Yout ping-pong (in-place
// would race across blocks). Swizzle byte ^= (row&7)<<4 : 16-way -> 2-way conflict.
template<int LAYER>
__global__ __launch_bounds__(256) void k_aggemm(const uint2* __restrict__ Yin,
                                                const int* __restrict__ rowoff,
                                                const int* __restrict__ ssrc,
                                                const float* __restrict__ snorm,
                                                const float* __restrict__ dinv,
                                                const float* __restrict__ bias,
                                                const float* __restrict__ fcW,
                                                float* __restrict__ sArr, float invS,
                                                const unsigned short* __restrict__ Wt,
                                                unsigned int* __restrict__ Yout, float Sout,
                                                int N, int rowsTot) {
    __shared__ unsigned short sX[64 * 64];   // 8 KiB, bf16 [row][k], swizzled
    __shared__ float sOut[4][16 * 68];
    int tid = threadIdx.x;
    int w = tid >> 6, lane = tid & 63;
    int b = lane >> 3, hb = (lane & 7) * 8;

    float bv[8], wv[8];
#pragma unroll
    for (int k = 0; k < 8; ++k) { bv[k] = bias[hb + k]; wv[k] = fcW[3 * (hb + k) + LAYER]; }

    int n0 = blockIdx.x * 8;
#pragma unroll
    for (int j = 0; j < 2; ++j) {
        int ln = w * 2 + j;
        int n = n0 + ln;
        int r = ln * 8 + b;
        unsigned int byte = (unsigned int)(r * 128 + hb * 2) ^ ((unsigned int)(r & 7) << 4);
        short8_t* dst = (short8_t*)((char*)sX + byte);
        if (n < N) {
            float acc[8];
            agg_node<LAYER>(Yin, rowoff, ssrc, snorm, dinv, bv, wv, sArr, invS, n, lane, acc);
            ABFrag xr;
#pragma unroll
            for (int k = 0; k < 8; ++k) xr.u[k] = f2bf(acc[k]);
            *dst = xr.s;
        } else {
            ABFrag xr;
#pragma unroll
            for (int k = 0; k < 8; ++k) xr.u[k] = 0;
            *dst = xr.s;
        }
    }
    __syncthreads();

    // ---- GEMM on the block's 64 rows from LDS ----
    int cc = lane & 15, kg = (lane >> 4) * 8;
    float* so = &sOut[w][0];
    ABFrag bf[2][4];
#pragma unroll
    for (int h = 0; h < 2; ++h)
#pragma unroll
        for (int c = 0; c < 4; ++c)
            bf[h][c].s = *(const short8_t*)&Wt[(size_t)(c * 16 + cc) * 64 + h * 32 + kg];

    int rA = w * 16 + (lane & 15);
    ABFrag a[2];
#pragma unroll
    for (int h = 0; h < 2; ++h) {
        unsigned int byte = (unsigned int)(rA * 128 + (h * 32 + kg) * 2) ^ ((unsigned int)(rA & 7) << 4);
        a[h].s = *(const short8_t*)((const char*)sX + byte);
    }
    f32x4 acc4[4] = {f32x4{}, f32x4{}, f32x4{}, f32x4{}};
#pragma unroll
    for (int h = 0; h < 2; ++h)
#pragma unroll
        for (int c = 0; c < 4; ++c)
            acc4[c] = __builtin_amdgcn_mfma_f32_16x16x32_bf16(a[h].s, bf[h][c].s, acc4[c], 0, 0, 0);
    gemm_epilogue(so, acc4, Yout, Sout, blockIdx.x * 64 + w * 16, rowsTot, lane);
}

// ---------------- layer-3 aggregation (no following GEMM; proven R2) ----------------

template<int LAYER>
__global__ __launch_bounds__(256) void k_agg(const uint2* __restrict__ Y,
                                             const int* __restrict__ rowoff,
                                             const int* __restrict__ ssrc,
                                             const float* __restrict__ snorm,
                                             const float* __restrict__ dinv,
                                             const float* __restrict__ bias,
                                             const float* __restrict__ fcW,
                                             float* __restrict__ sArr,
                                             float invS, int N) {
    int n = blockIdx.x * 4 + (threadIdx.x >> 6);
    if (n >= N) return;
    int lane = threadIdx.x & 63;
    int hb = (lane & 7) * 8;
    float bv[8], wv[8];
#pragma unroll
    for (int k = 0; k < 8; ++k) { bv[k] = bias[hb + k]; wv[k] = fcW[3 * (hb + k) + LAYER]; }
    float acc[8];
    agg_node<LAYER>(Y, rowoff, ssrc, snorm, dinv, bv, wv, sArr, invS, n, lane, acc);
}

// ---------------- fused pooling + l1 + head (proven R4) ----------------

__global__ __launch_bounds__(128) void k_l1pool(const float* __restrict__ sArr,
                                                const int* __restrict__ coff,
                                                const int* __restrict__ crow,
                                                const float* __restrict__ fcb,
                                                const float* __restrict__ l1W,
                                                float* __restrict__ hpre,
                                                int* __restrict__ done,
                                                const float* __restrict__ l1b,
                                                const float* __restrict__ l2W,
                                                const float* __restrict__ l2b,
                                                float* __restrict__ out,
                                                int NC, int HFC, int bs, int NCLS,
                                                int CHUNK, int nBlocks) {
    __shared__ float hl[64];
    int b = blockIdx.y;
    int c0 = blockIdx.x * CHUNK;
    int j = threadIdx.x;
    int cend = min(c0 + CHUNK, NC);
    {
        int w = j >> 6, lane = j & 63, q = lane >> 4, s = lane & 15;
        float fcb0 = fcb[0];
        for (int c = c0 + w * 4 + q; c < cend; c += 8) {
            int beg = coff[c], end = coff[c + 1];
            float acc = 0.f;
            for (int i = beg + s; i < end; i += 16)
                acc += sArr[(size_t)crow[i] * 8 + b];
            acc += __shfl_down(acc, 8, 16);
            acc += __shfl_down(acc, 4, 16);
            acc += __shfl_down(acc, 2, 16);
            acc += __shfl_down(acc, 1, 16);
            if (s == 0)
                hl[c - c0] = acc / fmaxf((float)(end - beg), 1.f) + fcb0;
        }
    }
    __syncthreads();
    float acc = 0.f;
    for (int c = c0; c < cend; ++c) acc = fmaf(hl[c - c0], l1W[(size_t)c * HFC + j], acc);
    atomicAdd(&hpre[(size_t)b * HFC + j], acc);

    __threadfence();
    __syncthreads();
    __shared__ int amLast;
    if (j == 0) amLast = (atomicAdd(done, 1) == nBlocks - 1);
    __syncthreads();
    if (!amLast) return;
    __threadfence();

    __shared__ float sZ[64];
    int g = j >> 3, l8 = j & 7;
    int nout = bs * NCLS;
    float v = 0.f;
    int b2 = g / NCLS, k2 = g - b2 * NCLS;
    if (g < nout) {
        for (int jj = l8; jj < HFC; jj += 8) {
            float h = fmaxf(hpre[(size_t)b2 * HFC + jj] + l1b[jj], 0.f);
            v = fmaf(h, l2W[(size_t)jj * NCLS + k2], v);
        }
    }
    v += __shfl_down(v, 4, 8);
    v += __shfl_down(v, 2, 8);
    v += __shfl_down(v, 1, 8);
    if (l8 == 0 && g < nout) sZ[g] = v + l2b[k2];
    __syncthreads();
    if (j < bs) {
        float m = -1e30f;
        for (int c = 0; c < NCLS; ++c) m = fmaxf(m, sZ[j * NCLS + c]);
        float s = 0.f;
        for (int c = 0; c < NCLS; ++c) s += expf(sZ[j * NCLS + c] - m);
        float lse = m + logf(s);
        for (int c = 0; c < NCLS; ++c) out[j * NCLS + c] = sZ[j * NCLS + c] - lse;
    }
}

// ---------------- launcher ----------------

extern "C" void kernel_launch(void* const* d_in, const int* in_sizes, int n_in,
                              void* d_out, int out_size, void* d_ws, size_t ws_size,
                              hipStream_t stream) {
    const float* x   = (const float*)d_in[0];
    const int* eidx  = (const int*)d_in[2];
    const int* prow  = (const int*)d_in[3];
    const int* pcol  = (const int*)d_in[4];
    const float* W1  = (const float*)d_in[5];
    const float* b1  = (const float*)d_in[6];
    const float* W2  = (const float*)d_in[7];
    const float* b2  = (const float*)d_in[8];
    const float* W3  = (const float*)d_in[9];
    const float* b3  = (const float*)d_in[10];
    const float* fcW = (const float*)d_in[11];
    const float* fcb = (const float*)d_in[12];
    const float* l1W = (const float*)d_in[13];
    const float* l1b = (const float*)d_in[14];
    const float* l2W = (const float*)d_in[15];
    const float* l2b = (const float*)d_in[16];
    float* out = (float*)d_out;

    const int bs   = in_sizes[1];                 // 8
    const int E    = in_sizes[2] / 2;
    const int P    = in_sizes[3];
    const int N    = in_sizes[0] / (bs * HID);
    const int HFC  = in_sizes[14];                // 128
    const int NC   = in_sizes[13] / HFC;          // 1000
    const int NCLS = in_sizes[15] / HFC;          // 2
    const int rows = N * bs;

    const int* esrc = eidx;
    const int* edst = eidx + E;

    size_t off = 0;
    auto alloc = [&](size_t bytes) -> void* {
        void* r = (char*)d_ws + off;
        off += (bytes + 255) & ~(size_t)255;
        return r;
    };
    // ---- zero region (one memset) ----
    char* zbase   = (char*)d_ws;
    int*   deg    = (int*)  alloc((size_t)N * 4);
    int*   fill   = (int*)  alloc((size_t)N * 4);
    int*   ccnt   = (int*)  alloc((size_t)NC * 4);
    int*   cfill  = (int*)  alloc((size_t)NC * 4);
    float* hpre   = (float*)alloc((size_t)bs * HFC * 4);
    int*   done   = (int*)  alloc(4);
    size_t zspan  = off;
    // ---- rest ----
    float* dinv   = (float*)alloc((size_t)N * 4);
    int*   rowoff = (int*)  alloc(((size_t)N + 1) * 4);
    int*   coff   = (int*)  alloc(((size_t)NC + 1) * 4);
    int*   crow   = (int*)  alloc((size_t)P * 4);
    int*   ssrc   = (int*)  alloc((size_t)E * 4);
    float* snorm  = (float*)alloc((size_t)E * 4);
    unsigned int* Yqa  = (unsigned int*)alloc((size_t)rows * HID);
    unsigned int* Yqb  = (unsigned int*)alloc((size_t)rows * HID);
    float* sArr   = (float*)alloc((size_t)rows * 4);
    unsigned short* Wt = (unsigned short*)alloc((size_t)2 * 64 * 64 * 2);

    hipMemsetAsync(zbase, 0, zspan, stream);

    const float S1 = 1.f,  iS1 = 1.f;
    const float S2 = 16.f, iS2 = 1.f / 16.f;
    const float S3 = 128.f, iS3 = 1.f / 128.f;

    int gG2 = (rows + 127) / 128;   // 946
    int gF  = (N + 7) / 8;          // 1892 (aggemm blocks: 8 nodes = 64 rows)
    int gA  = (N + 3) / 4;
    int gPre = 512;

    // dispatch 1: GEMM1 (x, W1-via-LDS) || degree/col counts + Wt(W2,W3)
    k_fused1<<<gG2 + gPre, 256, 0, stream>>>(x, W1, Yqa, S1, N, rows, gG2,
                                             edst, deg, E, pcol, ccnt, P, W2, W3, Wt);
    k_pre_scan<<<64, 256, 0, stream>>>(deg, rowoff, N, ccnt, coff, NC, dinv);
    k_pre_scatter<<<gPre, 256, 0, stream>>>(esrc, edst, dinv, rowoff, fill, ssrc, snorm, E,
                                            prow, pcol, coff, cfill, crow, P);

    // fused agg1+gemm2 (Yqa -> Yqb), agg2+gemm3 (Yqb -> Yqa), agg3
    k_aggemm<0><<<gF, 256, 0, stream>>>((const uint2*)Yqa, rowoff, ssrc, snorm, dinv, b1, fcW,
                                        sArr, iS1, Wt, Yqb, S2, N, rows);
    k_aggemm<1><<<gF, 256, 0, stream>>>((const uint2*)Yqb, rowoff, ssrc, snorm, dinv, b2, fcW,
                                        sArr, iS2, Wt + 4096, Yqa, S3, N, rows);
    k_agg<2><<<gA, 256, 0, stream>>>((const uint2*)Yqa, rowoff, ssrc, snorm, dinv, b3, fcW,
                                     sArr, iS3, N);

    const int CHUNK = 40;
    dim3 gL1((NC + CHUNK - 1) / CHUNK, bs);
    int nBlocks = gL1.x * gL1.y;   // 200
    k_l1pool<<<gL1, 128, 0, stream>>>(sArr, coff, crow, fcb, l1W, hpre, done,
                                      l1b, l2W, l2b, out, NC, HFC, bs, NCLS, CHUNK, nBlocks);
}

// Round 7
// 341.885 us; speedup vs baseline: 2.8805x; 1.0250x over previous
//
#include <hip/hip_runtime.h>
#include <hip/hip_bf16.h>
#include <hip/hip_fp16.h>
#include <math.h>

#define HID 64

#if defined(__has_builtin)
#if __has_builtin(__builtin_amdgcn_cvt_pk_f32_fp8) && __has_builtin(__builtin_amdgcn_cvt_pk_fp8_f32)
#define HWFP8 1
#endif
#endif

typedef float vfloat2 __attribute__((ext_vector_type(2)));
typedef __attribute__((ext_vector_type(8))) short short8_t;   // 8 bf16 (4 VGPRs)
typedef __attribute__((ext_vector_type(4))) float f32x4;

union ABFrag { short8_t s; unsigned short u[8]; };

// ---------------- helpers ----------------

__device__ __forceinline__ unsigned short f2bf(float x) {
    unsigned int u = __float_as_uint(x);
    unsigned int r = u + 0x7fffu + ((u >> 16) & 1u);   // RNE
    return (unsigned short)(r >> 16);
}

#ifndef HWFP8
__device__ __forceinline__ unsigned int enc8_sw(float a) {
    unsigned short hb = __half_as_ushort(__float2half(a));
    unsigned int r = (unsigned int)hb + 0x7fu + ((hb >> 8) & 1u);
    return (r >> 8) & 0xffu;
}
__device__ __forceinline__ float dec8_sw(unsigned int b) {
    return __half2float(__ushort_as_half((unsigned short)(b << 8)));
}
#endif

__device__ __forceinline__ unsigned int enc4(float a, float b, float c, float d) {
#ifdef HWFP8
    int r = __builtin_amdgcn_cvt_pk_fp8_f32(a, b, 0, false);
    r = __builtin_amdgcn_cvt_pk_fp8_f32(c, d, r, true);
    return (unsigned int)r;
#else
    return enc8_sw(a) | (enc8_sw(b) << 8) | (enc8_sw(c) << 16) | (enc8_sw(d) << 24);
#endif
}

__device__ __forceinline__ void dec4(unsigned int w, float* f) {
#ifdef HWFP8
    vfloat2 a = __builtin_amdgcn_cvt_pk_f32_fp8((int)w, false);
    vfloat2 b = __builtin_amdgcn_cvt_pk_f32_fp8((int)w, true);
    f[0] = a.x; f[1] = a.y; f[2] = b.x; f[3] = b.y;
#else
    f[0] = dec8_sw(w & 0xffu); f[1] = dec8_sw((w >> 8) & 0xffu);
    f[2] = dec8_sw((w >> 16) & 0xffu); f[3] = dec8_sw(w >> 24);
#endif
}

__device__ __forceinline__ void dec8(uint2 g, float* f) {
    dec4(g.x, f);
    dec4(g.y, f + 4);
}

// ---------------- GEMM epilogue (per-wave LDS transpose + fp8 pack) ----------------
__device__ __forceinline__ void gemm_epilogue(float* so, const f32x4* acc,
                                              unsigned int* Yq, float S,
                                              int r0w, int rowsTot, int lane) {
    int cc = lane & 15;
    int cr = (lane >> 4) * 4;
#pragma unroll
    for (int c = 0; c < 4; ++c) {
        so[(cr + 0) * 68 + c * 16 + cc] = acc[c][0];
        so[(cr + 1) * 68 + c * 16 + cc] = acc[c][1];
        so[(cr + 2) * 68 + c * 16 + cc] = acc[c][2];
        so[(cr + 3) * 68 + c * 16 + cc] = acc[c][3];
    }
    __syncthreads();
#pragma unroll
    for (int i = 0; i < 4; ++i) {
        int idx = lane + i * 64;
        int row = idx >> 4, ci = idx & 15;
        int grow = r0w + row;
        if (grow < rowsTot) {
            float4 v = *(const float4*)&so[row * 68 + ci * 4];
            Yq[(size_t)grow * 16 + ci] = enc4(v.x * S, v.y * S, v.z * S, v.w * S);
        }
    }
}

// ---------------- fused dispatch 1: GEMM1 (x fp32, W1 via LDS) || pre-count ----------------
__global__ __launch_bounds__(256) void k_fused1(const float* __restrict__ x,
                                                const float* __restrict__ W1,
                                                unsigned int* __restrict__ Yq,
                                                float S, int N, int rowsTot, int gGf,
                                                const int* __restrict__ edst, int* __restrict__ deg, int E,
                                                const int* __restrict__ pcol, int* __restrict__ ccnt, int P,
                                                const float* __restrict__ W2, const float* __restrict__ W3,
                                                unsigned short* __restrict__ Wt) {
    __shared__ float sOut[4][16 * 68];
    __shared__ unsigned short sW[4096];   // W1 bf16, [c][k]
    int tid = threadIdx.x;
    if ((int)blockIdx.x < gGf) {
        int w = tid >> 6, lane = tid & 63;
        int cc = lane & 15, kg = (lane >> 4) * 8;
        float* so = &sOut[w][0];
#pragma unroll
        for (int i = 0; i < 16; ++i) {
            int idx = i * 256 + tid;
            int k = idx >> 6, c = idx & 63;
            sW[c * 64 + k] = f2bf(W1[idx]);
        }
        __syncthreads();
        ABFrag bf[2][4];
#pragma unroll
        for (int h = 0; h < 2; ++h)
#pragma unroll
            for (int c = 0; c < 4; ++c)
                bf[h][c].s = *(const short8_t*)&sW[(c * 16 + cc) * 64 + h * 32 + kg];

        int base = blockIdx.x * 128;
        ABFrag a[2];
        auto loadA = [&](int rA, ABFrag* dst) {
#pragma unroll
            for (int h = 0; h < 2; ++h) {
                if (rA < rowsTot) {
                    int n = rA >> 3, b = rA & 7;
                    const float* p = &x[((size_t)b * N + n) * 64 + h * 32 + kg];
                    float4 v0 = *(const float4*)p;
                    float4 v1 = *(const float4*)(p + 4);
                    dst[h].u[0] = f2bf(v0.x); dst[h].u[1] = f2bf(v0.y);
                    dst[h].u[2] = f2bf(v0.z); dst[h].u[3] = f2bf(v0.w);
                    dst[h].u[4] = f2bf(v1.x); dst[h].u[5] = f2bf(v1.y);
                    dst[h].u[6] = f2bf(v1.z); dst[h].u[7] = f2bf(v1.w);
                } else {
#pragma unroll
                    for (int j = 0; j < 8; ++j) dst[h].u[j] = 0;
                }
            }
        };
        loadA(base + w * 16 + (lane & 15), a);
#pragma unroll
        for (int t = 0; t < 2; ++t) {
            ABFrag an[2];
            if (t < 1) loadA(base + 64 + w * 16 + (lane & 15), an);
            f32x4 acc[4] = {f32x4{}, f32x4{}, f32x4{}, f32x4{}};
#pragma unroll
            for (int h = 0; h < 2; ++h)
#pragma unroll
                for (int c = 0; c < 4; ++c)
                    acc[c] = __builtin_amdgcn_mfma_f32_16x16x32_bf16(a[h].s, bf[h][c].s, acc[c], 0, 0, 0);
            gemm_epilogue(so, acc, Yq, S, base + t * 64 + w * 16, rowsTot, lane);
            if (t < 1) { a[0] = an[0]; a[1] = an[1]; __syncthreads(); }
        }
    } else {
        int cb = blockIdx.x - gGf;
        int nCB = gridDim.x - gGf;
        int gth = cb * 256 + tid;
        int GT = nCB * 256;
        for (int e = gth; e < E; e += GT) atomicAdd(&deg[edst[e]], 1);
        for (int p = gth; p < P; p += GT) atomicAdd(&ccnt[pcol[p]], 1);
        for (int i = gth; i < 2 * 4096; i += GT) {
            int l = i >> 12, r = i & 4095;
            int k = r >> 6, c = r & 63;
            const float* W = (l == 0) ? W2 : W3;
            Wt[(l << 12) + c * 64 + k] = f2bf(W[r]);
        }
    }
}

// ---------------- remaining preprocessing (proven R2) ----------------

__global__ __launch_bounds__(256) void k_pre_scan(const int* __restrict__ deg, int* __restrict__ rowoff, int N,
                                                  const int* __restrict__ ccnt, int* __restrict__ coff, int NC,
                                                  float* __restrict__ dinv) {
    __shared__ int part[256];
    int t = threadIdx.x;
    int gth = blockIdx.x * blockDim.x + t;
    int GT = gridDim.x * blockDim.x;
    for (int i = gth; i < N; i += GT) dinv[i] = rsqrtf((float)(deg[i] + 1));

    const int* cnt = nullptr; int* off = nullptr; int n = 0;
    if (blockIdx.x == 0)      { cnt = deg;  off = rowoff; n = N; }
    else if (blockIdx.x == 1) { cnt = ccnt; off = coff;   n = NC; }
    else return;

    int CH = (n + 255) >> 8;
    int lo = min(t * CH, n), hi = min(lo + CH, n);
    int sum = 0;
    for (int i = lo; i < hi; ++i) sum += cnt[i];
    part[t] = sum;
    __syncthreads();
    for (int o = 1; o < 256; o <<= 1) {
        int v = (t >= o) ? part[t - o] : 0;
        __syncthreads();
        part[t] += v;
        __syncthreads();
    }
    int run = (t == 0) ? 0 : part[t - 1];
    for (int i = lo; i < hi; ++i) { off[i] = run; run += cnt[i]; }
    if (t == 255) off[n] = run;
}

__global__ __launch_bounds__(256) void k_pre_scatter(const int* __restrict__ esrc, const int* __restrict__ edst,
                                                     const float* __restrict__ dinv, const int* __restrict__ rowoff,
                                                     int* __restrict__ fill, int* __restrict__ ssrc,
                                                     float* __restrict__ snorm, int E,
                                                     const int* __restrict__ prow, const int* __restrict__ pcol,
                                                     const int* __restrict__ coff, int* __restrict__ cfill,
                                                     int* __restrict__ crow, int P) {
    int gth = blockIdx.x * blockDim.x + threadIdx.x;
    int GT = gridDim.x * blockDim.x;
    for (int e = gth; e < E; e += GT) {
        int s = esrc[e], d = edst[e];
        int pos = rowoff[d] + atomicAdd(&fill[d], 1);
        ssrc[pos]  = s;
        snorm[pos] = dinv[s] * dinv[d];
    }
    for (int p = gth; p < P; p += GT) {
        int c = pcol[p];
        int pos = coff[c] + atomicAdd(&cfill[c], 1);
        crow[pos] = prow[p];
    }
}

// ---------------- agg core: padded 8-deep pipeline, no serial remainder ----------------
// deg_avg = E/N ~ 16: the old "batched + serial remainder" structure exposed
// ~4 extra full-latency hops per node (remainder 1-at-a-time + serial self row).
// Padded batches (clamped idx, zero weight -> fmaf(0,f,acc)==acc exactly, same
// summation order) + self-row load issued before the loop and consumed after
// batch-0's loads are in flight.
template<int LAYER>
__device__ __forceinline__ void agg_node(const uint2* __restrict__ Y,
                                         const int* __restrict__ rowoff,
                                         const int* __restrict__ ssrc,
                                         const float* __restrict__ snorm,
                                         const float* __restrict__ dinv,
                                         const float* bv, const float* wv,
                                         float* __restrict__ sArr,
                                         float invS, int n, int lane,
                                         float* accOut) {
    float dn = dinv[n];
    float w0 = dn * dn;
    int beg = rowoff[n], end = rowoff[n + 1];

    uint2 gs = Y[(size_t)n * 64 + lane];       // self row: issue first
    float acc[8] = {0.f, 0.f, 0.f, 0.f, 0.f, 0.f, 0.f, 0.f};
    float f[8];
    bool haveSelf = false;

    for (int i = beg; i < end; i += 8) {
        int   sI[8];
        float wI[8];
        uint2 g[8];
#pragma unroll
        for (int u = 0; u < 8; ++u) {
            int valid = (i + u < end);
            int idx = valid ? (i + u) : i;
            sI[u] = ssrc[idx];
            wI[u] = valid ? snorm[idx] : 0.f;
        }
#pragma unroll
        for (int u = 0; u < 8; ++u) g[u] = Y[(size_t)sI[u] * 64 + lane];
        if (!haveSelf) {                        // consume self under batch-0 latency
            dec8(gs, f);
#pragma unroll
            for (int k = 0; k < 8; ++k) acc[k] = w0 * f[k];
            haveSelf = true;
        }
#pragma unroll
        for (int u = 0; u < 8; ++u) {
            dec8(g[u], f);
#pragma unroll
            for (int k = 0; k < 8; ++k) acc[k] = fmaf(wI[u], f[k], acc[k]);
        }
    }
    if (!haveSelf) {                            // deg == 0
        dec8(gs, f);
#pragma unroll
        for (int k = 0; k < 8; ++k) acc[k] = w0 * f[k];
    }

    float sv = 0.f;
#pragma unroll
    for (int k = 0; k < 8; ++k) {
        float o = fmaxf(fmaf(acc[k], invS, bv[k]), 0.f);
        accOut[k] = o;
        sv = fmaf(o, wv[k], sv);
    }
    sv += __shfl_down(sv, 4, 64);
    sv += __shfl_down(sv, 2, 64);
    sv += __shfl_down(sv, 1, 64);
    if ((lane & 7) == 0) {
        int b = lane >> 3;
        float* sp = sArr + (size_t)n * 8 + b;
        if (LAYER == 0) *sp = sv;
        else            *sp += sv;
    }
}

// ---------------- fused agg(L) + gemm(L+1): 8 nodes = 64 rows per block ----------------
// sX unioned into sOut (LDS 25600 -> 17408: 6 -> 9 LDS-limited blocks/CU);
// extra barrier after A-frag reads protects the aliasing.
template<int LAYER>
__global__ __launch_bounds__(256) void k_aggemm(const uint2* __restrict__ Yin,
                                                const int* __restrict__ rowoff,
                                                const int* __restrict__ ssrc,
                                                const float* __restrict__ snorm,
                                                const float* __restrict__ dinv,
                                                const float* __restrict__ bias,
                                                const float* __restrict__ fcW,
                                                float* __restrict__ sArr, float invS,
                                                const unsigned short* __restrict__ Wt,
                                                unsigned int* __restrict__ Yout, float Sout,
                                                int N, int rowsTot) {
    struct ShU { union { unsigned short sX[64 * 64]; float sOut[4][16 * 68]; }; };
    __shared__ ShU sh;
    int tid = threadIdx.x;
    int w = tid >> 6, lane = tid & 63;
    int b = lane >> 3, hb = (lane & 7) * 8;

    float bv[8], wv[8];
#pragma unroll
    for (int k = 0; k < 8; ++k) { bv[k] = bias[hb + k]; wv[k] = fcW[3 * (hb + k) + LAYER]; }

    int n0 = blockIdx.x * 8;
#pragma unroll
    for (int j = 0; j < 2; ++j) {
        int ln = w * 2 + j;
        int n = n0 + ln;
        int r = ln * 8 + b;
        unsigned int byte = (unsigned int)(r * 128 + hb * 2) ^ ((unsigned int)(r & 7) << 4);
        short8_t* dst = (short8_t*)((char*)sh.sX + byte);
        if (n < N) {
            float acc[8];
            agg_node<LAYER>(Yin, rowoff, ssrc, snorm, dinv, bv, wv, sArr, invS, n, lane, acc);
            ABFrag xr;
#pragma unroll
            for (int k = 0; k < 8; ++k) xr.u[k] = f2bf(acc[k]);
            *dst = xr.s;
        } else {
            ABFrag xr;
#pragma unroll
            for (int k = 0; k < 8; ++k) xr.u[k] = 0;
            *dst = xr.s;
        }
    }
    __syncthreads();

    // ---- GEMM on the block's 64 rows from LDS ----
    int cc = lane & 15, kg = (lane >> 4) * 8;
    ABFrag bf[2][4];
#pragma unroll
    for (int h = 0; h < 2; ++h)
#pragma unroll
        for (int c = 0; c < 4; ++c)
            bf[h][c].s = *(const short8_t*)&Wt[(size_t)(c * 16 + cc) * 64 + h * 32 + kg];

    int rA = w * 16 + (lane & 15);
    ABFrag a[2];
#pragma unroll
    for (int h = 0; h < 2; ++h) {
        unsigned int byte = (unsigned int)(rA * 128 + (h * 32 + kg) * 2) ^ ((unsigned int)(rA & 7) << 4);
        a[h].s = *(const short8_t*)((const char*)sh.sX + byte);
    }
    f32x4 acc4[4] = {f32x4{}, f32x4{}, f32x4{}, f32x4{}};
#pragma unroll
    for (int h = 0; h < 2; ++h)
#pragma unroll
        for (int c = 0; c < 4; ++c)
            acc4[c] = __builtin_amdgcn_mfma_f32_16x16x32_bf16(a[h].s, bf[h][c].s, acc4[c], 0, 0, 0);
    __syncthreads();   // all sX reads done before sOut (aliased) is written
    gemm_epilogue(&sh.sOut[w][0], acc4, Yout, Sout, blockIdx.x * 64 + w * 16, rowsTot, lane);
}

// ---------------- layer-3 aggregation (no following GEMM) ----------------

template<int LAYER>
__global__ __launch_bounds__(256) void k_agg(const uint2* __restrict__ Y,
                                             const int* __restrict__ rowoff,
                                             const int* __restrict__ ssrc,
                                             const float* __restrict__ snorm,
                                             const float* __restrict__ dinv,
                                             const float* __restrict__ bias,
                                             const float* __restrict__ fcW,
                                             float* __restrict__ sArr,
                                             float invS, int N) {
    int n = blockIdx.x * 4 + (threadIdx.x >> 6);
    if (n >= N) return;
    int lane = threadIdx.x & 63;
    int hb = (lane & 7) * 8;
    float bv[8], wv[8];
#pragma unroll
    for (int k = 0; k < 8; ++k) { bv[k] = bias[hb + k]; wv[k] = fcW[3 * (hb + k) + LAYER]; }
    float acc[8];
    agg_node<LAYER>(Y, rowoff, ssrc, snorm, dinv, bv, wv, sArr, invS, n, lane, acc);
}

// ---------------- fused pooling + l1 + head (proven R4) ----------------

__global__ __launch_bounds__(128) void k_l1pool(const float* __restrict__ sArr,
                                                const int* __restrict__ coff,
                                                const int* __restrict__ crow,
                                                const float* __restrict__ fcb,
                                                const float* __restrict__ l1W,
                                                float* __restrict__ hpre,
                                                int* __restrict__ done,
                                                const float* __restrict__ l1b,
                                                const float* __restrict__ l2W,
                                                const float* __restrict__ l2b,
                                                float* __restrict__ out,
                                                int NC, int HFC, int bs, int NCLS,
                                                int CHUNK, int nBlocks) {
    __shared__ float hl[64];
    int b = blockIdx.y;
    int c0 = blockIdx.x * CHUNK;
    int j = threadIdx.x;
    int cend = min(c0 + CHUNK, NC);
    {
        int w = j >> 6, lane = j & 63, q = lane >> 4, s = lane & 15;
        float fcb0 = fcb[0];
        for (int c = c0 + w * 4 + q; c < cend; c += 8) {
            int beg = coff[c], end = coff[c + 1];
            float acc = 0.f;
            for (int i = beg + s; i < end; i += 16)
                acc += sArr[(size_t)crow[i] * 8 + b];
            acc += __shfl_down(acc, 8, 16);
            acc += __shfl_down(acc, 4, 16);
            acc += __shfl_down(acc, 2, 16);
            acc += __shfl_down(acc, 1, 16);
            if (s == 0)
                hl[c - c0] = acc / fmaxf((float)(end - beg), 1.f) + fcb0;
        }
    }
    __syncthreads();
    float acc = 0.f;
    for (int c = c0; c < cend; ++c) acc = fmaf(hl[c - c0], l1W[(size_t)c * HFC + j], acc);
    atomicAdd(&hpre[(size_t)b * HFC + j], acc);

    __threadfence();
    __syncthreads();
    __shared__ int amLast;
    if (j == 0) amLast = (atomicAdd(done, 1) == nBlocks - 1);
    __syncthreads();
    if (!amLast) return;
    __threadfence();

    __shared__ float sZ[64];
    int g = j >> 3, l8 = j & 7;
    int nout = bs * NCLS;
    float v = 0.f;
    int b2 = g / NCLS, k2 = g - b2 * NCLS;
    if (g < nout) {
        for (int jj = l8; jj < HFC; jj += 8) {
            float h = fmaxf(hpre[(size_t)b2 * HFC + jj] + l1b[jj], 0.f);
            v = fmaf(h, l2W[(size_t)jj * NCLS + k2], v);
        }
    }
    v += __shfl_down(v, 4, 8);
    v += __shfl_down(v, 2, 8);
    v += __shfl_down(v, 1, 8);
    if (l8 == 0 && g < nout) sZ[g] = v + l2b[k2];
    __syncthreads();
    if (j < bs) {
        float m = -1e30f;
        for (int c = 0; c < NCLS; ++c) m = fmaxf(m, sZ[j * NCLS + c]);
        float s = 0.f;
        for (int c = 0; c < NCLS; ++c) s += expf(sZ[j * NCLS + c] - m);
        float lse = m + logf(s);
        for (int c = 0; c < NCLS; ++c) out[j * NCLS + c] = sZ[j * NCLS + c] - lse;
    }
}

// ---------------- launcher ----------------

extern "C" void kernel_launch(void* const* d_in, const int* in_sizes, int n_in,
                              void* d_out, int out_size, void* d_ws, size_t ws_size,
                              hipStream_t stream) {
    const float* x   = (const float*)d_in[0];
    const int* eidx  = (const int*)d_in[2];
    const int* prow  = (const int*)d_in[3];
    const int* pcol  = (const int*)d_in[4];
    const float* W1  = (const float*)d_in[5];
    const float* b1  = (const float*)d_in[6];
    const float* W2  = (const float*)d_in[7];
    const float* b2  = (const float*)d_in[8];
    const float* W3  = (const float*)d_in[9];
    const float* b3  = (const float*)d_in[10];
    const float* fcW = (const float*)d_in[11];
    const float* fcb = (const float*)d_in[12];
    const float* l1W = (const float*)d_in[13];
    const float* l1b = (const float*)d_in[14];
    const float* l2W = (const float*)d_in[15];
    const float* l2b = (const float*)d_in[16];
    float* out = (float*)d_out;

    const int bs   = in_sizes[1];                 // 8
    const int E    = in_sizes[2] / 2;
    const int P    = in_sizes[3];
    const int N    = in_sizes[0] / (bs * HID);
    const int HFC  = in_sizes[14];                // 128
    const int NC   = in_sizes[13] / HFC;          // 1000
    const int NCLS = in_sizes[15] / HFC;          // 2
    const int rows = N * bs;

    const int* esrc = eidx;
    const int* edst = eidx + E;

    size_t off = 0;
    auto alloc = [&](size_t bytes) -> void* {
        void* r = (char*)d_ws + off;
        off += (bytes + 255) & ~(size_t)255;
        return r;
    };
    // ---- zero region (one memset) ----
    char* zbase   = (char*)d_ws;
    int*   deg    = (int*)  alloc((size_t)N * 4);
    int*   fill   = (int*)  alloc((size_t)N * 4);
    int*   ccnt   = (int*)  alloc((size_t)NC * 4);
    int*   cfill  = (int*)  alloc((size_t)NC * 4);
    float* hpre   = (float*)alloc((size_t)bs * HFC * 4);
    int*   done   = (int*)  alloc(4);
    size_t zspan  = off;
    // ---- rest ----
    float* dinv   = (float*)alloc((size_t)N * 4);
    int*   rowoff = (int*)  alloc(((size_t)N + 1) * 4);
    int*   coff   = (int*)  alloc(((size_t)NC + 1) * 4);
    int*   crow   = (int*)  alloc((size_t)P * 4);
    int*   ssrc   = (int*)  alloc((size_t)E * 4);
    float* snorm  = (float*)alloc((size_t)E * 4);
    unsigned int* Yqa  = (unsigned int*)alloc((size_t)rows * HID);
    unsigned int* Yqb  = (unsigned int*)alloc((size_t)rows * HID);
    float* sArr   = (float*)alloc((size_t)rows * 4);
    unsigned short* Wt = (unsigned short*)alloc((size_t)2 * 64 * 64 * 2);

    hipMemsetAsync(zbase, 0, zspan, stream);

    const float S1 = 1.f,  iS1 = 1.f;
    const float S2 = 16.f, iS2 = 1.f / 16.f;
    const float S3 = 128.f, iS3 = 1.f / 128.f;

    int gG2 = (rows + 127) / 128;   // 946
    int gF  = (N + 7) / 8;          // 1892 (aggemm blocks: 8 nodes = 64 rows)
    int gA  = (N + 3) / 4;
    int gPre = 512;

    // dispatch 1: GEMM1 (x, W1-via-LDS) || degree/col counts + Wt(W2,W3)
    k_fused1<<<gG2 + gPre, 256, 0, stream>>>(x, W1, Yqa, S1, N, rows, gG2,
                                             edst, deg, E, pcol, ccnt, P, W2, W3, Wt);
    k_pre_scan<<<64, 256, 0, stream>>>(deg, rowoff, N, ccnt, coff, NC, dinv);
    k_pre_scatter<<<gPre, 256, 0, stream>>>(esrc, edst, dinv, rowoff, fill, ssrc, snorm, E,
                                            prow, pcol, coff, cfill, crow, P);

    // fused agg1+gemm2 (Yqa -> Yqb), agg2+gemm3 (Yqb -> Yqa), agg3
    k_aggemm<0><<<gF, 256, 0, stream>>>((const uint2*)Yqa, rowoff, ssrc, snorm, dinv, b1, fcW,
                                        sArr, iS1, Wt, Yqb, S2, N, rows);
    k_aggemm<1><<<gF, 256, 0, stream>>>((const uint2*)Yqb, rowoff, ssrc, snorm, dinv, b2, fcW,
                                        sArr, iS2, Wt + 4096, Yqa, S3, N, rows);
    k_agg<2><<<gA, 256, 0, stream>>>((const uint2*)Yqa, rowoff, ssrc, snorm, dinv, b3, fcW,
                                     sArr, iS3, N);

    const int CHUNK = 40;
    dim3 gL1((NC + CHUNK - 1) / CHUNK, bs);
    int nBlocks = gL1.x * gL1.y;   // 200
    k_l1pool<<<gL1, 128, 0, stream>>>(sArr, coff, crow, fcb, l1W, hpre, done,
                                      l1b, l2W, l2b, out, NC, HFC, bs, NCLS, CHUNK, nBlocks);
}

// Round 8
// 327.124 us; speedup vs baseline: 3.0105x; 1.0451x over previous
//
#include <hip/hip_runtime.h>
#include <hip/hip_bf16.h>
#include <hip/hip_fp16.h>
#include <math.h>

#define HID 64

#if defined(__has_builtin)
#if __has_builtin(__builtin_amdgcn_cvt_pk_f32_fp8) && __has_builtin(__builtin_amdgcn_cvt_pk_fp8_f32)
#define HWFP8 1
#endif
#endif

typedef float vfloat2 __attribute__((ext_vector_type(2)));
typedef __attribute__((ext_vector_type(8))) short short8_t;   // 8 bf16 (4 VGPRs)
typedef __attribute__((ext_vector_type(4))) float f32x4;

union ABFrag { short8_t s; unsigned short u[8]; };

// ---------------- helpers ----------------

__device__ __forceinline__ unsigned short f2bf(float x) {
    unsigned int u = __float_as_uint(x);
    unsigned int r = u + 0x7fffu + ((u >> 16) & 1u);   // RNE
    return (unsigned short)(r >> 16);
}

#ifndef HWFP8
__device__ __forceinline__ unsigned int enc8_sw(float a) {
    unsigned short hb = __half_as_ushort(__float2half(a));
    unsigned int r = (unsigned int)hb + 0x7fu + ((hb >> 8) & 1u);
    return (r >> 8) & 0xffu;
}
__device__ __forceinline__ float dec8_sw(unsigned int b) {
    return __half2float(__ushort_as_half((unsigned short)(b << 8)));
}
#endif

__device__ __forceinline__ unsigned int enc4(float a, float b, float c, float d) {
#ifdef HWFP8
    int r = __builtin_amdgcn_cvt_pk_fp8_f32(a, b, 0, false);
    r = __builtin_amdgcn_cvt_pk_fp8_f32(c, d, r, true);
    return (unsigned int)r;
#else
    return enc8_sw(a) | (enc8_sw(b) << 8) | (enc8_sw(c) << 16) | (enc8_sw(d) << 24);
#endif
}

__device__ __forceinline__ void dec4(unsigned int w, float* f) {
#ifdef HWFP8
    vfloat2 a = __builtin_amdgcn_cvt_pk_f32_fp8((int)w, false);
    vfloat2 b = __builtin_amdgcn_cvt_pk_f32_fp8((int)w, true);
    f[0] = a.x; f[1] = a.y; f[2] = b.x; f[3] = b.y;
#else
    f[0] = dec8_sw(w & 0xffu); f[1] = dec8_sw((w >> 8) & 0xffu);
    f[2] = dec8_sw((w >> 16) & 0xffu); f[3] = dec8_sw(w >> 24);
#endif
}

__device__ __forceinline__ void dec8(uint2 g, float* f) {
    dec4(g.x, f);
    dec4(g.y, f + 4);
}

// ---------------- GEMM epilogue (per-wave LDS transpose + fp8 pack) ----------------
__device__ __forceinline__ void gemm_epilogue(float* so, const f32x4* acc,
                                              unsigned int* Yq, float S,
                                              int r0w, int rowsTot, int lane) {
    int cc = lane & 15;
    int cr = (lane >> 4) * 4;
#pragma unroll
    for (int c = 0; c < 4; ++c) {
        so[(cr + 0) * 68 + c * 16 + cc] = acc[c][0];
        so[(cr + 1) * 68 + c * 16 + cc] = acc[c][1];
        so[(cr + 2) * 68 + c * 16 + cc] = acc[c][2];
        so[(cr + 3) * 68 + c * 16 + cc] = acc[c][3];
    }
    __syncthreads();
#pragma unroll
    for (int i = 0; i < 4; ++i) {
        int idx = lane + i * 64;
        int row = idx >> 4, ci = idx & 15;
        int grow = r0w + row;
        if (grow < rowsTot) {
            float4 v = *(const float4*)&so[row * 68 + ci * 4];
            Yq[(size_t)grow * 16 + ci] = enc4(v.x * S, v.y * S, v.z * S, v.w * S);
        }
    }
}

// ---------------- fused dispatch 1: GEMM1 (x fp32, W1 via LDS) || pre-count ----------------
__global__ __launch_bounds__(256) void k_fused1(const float* __restrict__ x,
                                                const float* __restrict__ W1,
                                                unsigned int* __restrict__ Yq,
                                                float S, int N, int rowsTot, int gGf,
                                                const int* __restrict__ edst, int* __restrict__ deg, int E,
                                                const int* __restrict__ pcol, int* __restrict__ ccnt, int P,
                                                const float* __restrict__ W2, const float* __restrict__ W3,
                                                unsigned short* __restrict__ Wt) {
    __shared__ float sOut[4][16 * 68];
    __shared__ unsigned short sW[4096];   // W1 bf16, [c][k]
    int tid = threadIdx.x;
    if ((int)blockIdx.x < gGf) {
        int w = tid >> 6, lane = tid & 63;
        int cc = lane & 15, kg = (lane >> 4) * 8;
        float* so = &sOut[w][0];
#pragma unroll
        for (int i = 0; i < 16; ++i) {
            int idx = i * 256 + tid;
            int k = idx >> 6, c = idx & 63;
            sW[c * 64 + k] = f2bf(W1[idx]);
        }
        __syncthreads();
        ABFrag bf[2][4];
#pragma unroll
        for (int h = 0; h < 2; ++h)
#pragma unroll
            for (int c = 0; c < 4; ++c)
                bf[h][c].s = *(const short8_t*)&sW[(c * 16 + cc) * 64 + h * 32 + kg];

        int base = blockIdx.x * 128;
        ABFrag a[2];
        auto loadA = [&](int rA, ABFrag* dst) {
#pragma unroll
            for (int h = 0; h < 2; ++h) {
                if (rA < rowsTot) {
                    int n = rA >> 3, b = rA & 7;
                    const float* p = &x[((size_t)b * N + n) * 64 + h * 32 + kg];
                    float4 v0 = *(const float4*)p;
                    float4 v1 = *(const float4*)(p + 4);
                    dst[h].u[0] = f2bf(v0.x); dst[h].u[1] = f2bf(v0.y);
                    dst[h].u[2] = f2bf(v0.z); dst[h].u[3] = f2bf(v0.w);
                    dst[h].u[4] = f2bf(v1.x); dst[h].u[5] = f2bf(v1.y);
                    dst[h].u[6] = f2bf(v1.z); dst[h].u[7] = f2bf(v1.w);
                } else {
#pragma unroll
                    for (int j = 0; j < 8; ++j) dst[h].u[j] = 0;
                }
            }
        };
        loadA(base + w * 16 + (lane & 15), a);
#pragma unroll
        for (int t = 0; t < 2; ++t) {
            ABFrag an[2];
            if (t < 1) loadA(base + 64 + w * 16 + (lane & 15), an);
            f32x4 acc[4] = {f32x4{}, f32x4{}, f32x4{}, f32x4{}};
#pragma unroll
            for (int h = 0; h < 2; ++h)
#pragma unroll
                for (int c = 0; c < 4; ++c)
                    acc[c] = __builtin_amdgcn_mfma_f32_16x16x32_bf16(a[h].s, bf[h][c].s, acc[c], 0, 0, 0);
            gemm_epilogue(so, acc, Yq, S, base + t * 64 + w * 16, rowsTot, lane);
            if (t < 1) { a[0] = an[0]; a[1] = an[1]; __syncthreads(); }
        }
    } else {
        int cb = blockIdx.x - gGf;
        int nCB = gridDim.x - gGf;
        int gth = cb * 256 + tid;
        int GT = nCB * 256;
        for (int e = gth; e < E; e += GT) atomicAdd(&deg[edst[e]], 1);
        for (int p = gth; p < P; p += GT) atomicAdd(&ccnt[pcol[p]], 1);
        for (int i = gth; i < 2 * 4096; i += GT) {
            int l = i >> 12, r = i & 4095;
            int k = r >> 6, c = r & 63;
            const float* W = (l == 0) ? W2 : W3;
            Wt[(l << 12) + c * 64 + k] = f2bf(W[r]);
        }
    }
}

// ---------------- remaining preprocessing (proven R2) ----------------

__global__ __launch_bounds__(256) void k_pre_scan(const int* __restrict__ deg, int* __restrict__ rowoff, int N,
                                                  const int* __restrict__ ccnt, int* __restrict__ coff, int NC,
                                                  float* __restrict__ dinv) {
    __shared__ int part[256];
    int t = threadIdx.x;
    int gth = blockIdx.x * blockDim.x + t;
    int GT = gridDim.x * blockDim.x;
    for (int i = gth; i < N; i += GT) dinv[i] = rsqrtf((float)(deg[i] + 1));

    const int* cnt = nullptr; int* off = nullptr; int n = 0;
    if (blockIdx.x == 0)      { cnt = deg;  off = rowoff; n = N; }
    else if (blockIdx.x == 1) { cnt = ccnt; off = coff;   n = NC; }
    else return;

    int CH = (n + 255) >> 8;
    int lo = min(t * CH, n), hi = min(lo + CH, n);
    int sum = 0;
    for (int i = lo; i < hi; ++i) sum += cnt[i];
    part[t] = sum;
    __syncthreads();
    for (int o = 1; o < 256; o <<= 1) {
        int v = (t >= o) ? part[t - o] : 0;
        __syncthreads();
        part[t] += v;
        __syncthreads();
    }
    int run = (t == 0) ? 0 : part[t - 1];
    for (int i = lo; i < hi; ++i) { off[i] = run; run += cnt[i]; }
    if (t == 255) off[n] = run;
}

__global__ __launch_bounds__(256) void k_pre_scatter(const int* __restrict__ esrc, const int* __restrict__ edst,
                                                     const float* __restrict__ dinv, const int* __restrict__ rowoff,
                                                     int* __restrict__ fill, int* __restrict__ ssrc,
                                                     float* __restrict__ snorm, int E,
                                                     const int* __restrict__ prow, const int* __restrict__ pcol,
                                                     const int* __restrict__ coff, int* __restrict__ cfill,
                                                     int* __restrict__ crow, int P) {
    int gth = blockIdx.x * blockDim.x + threadIdx.x;
    int GT = gridDim.x * blockDim.x;
    for (int e = gth; e < E; e += GT) {
        int s = esrc[e], d = edst[e];
        int pos = rowoff[d] + atomicAdd(&fill[d], 1);
        ssrc[pos]  = s;
        snorm[pos] = dinv[s] * dinv[d];
    }
    for (int p = gth; p < P; p += GT) {
        int c = pcol[p];
        int pos = coff[c] + atomicAdd(&cfill[c], 1);
        crow[pos] = prow[p];
    }
}

// ---------------- agg core: padded 8-deep pipeline (proven R7) ----------------

template<int LAYER>
__device__ __forceinline__ void agg_node(const uint2* __restrict__ Y,
                                         const int* __restrict__ rowoff,
                                         const int* __restrict__ ssrc,
                                         const float* __restrict__ snorm,
                                         const float* __restrict__ dinv,
                                         const float* bv, const float* wv,
                                         float* __restrict__ sArr,
                                         float invS, int n, int lane,
                                         float* accOut) {
    float dn = dinv[n];
    float w0 = dn * dn;
    int beg = rowoff[n], end = rowoff[n + 1];

    uint2 gs = Y[(size_t)n * 64 + lane];       // self row: issue first
    float acc[8] = {0.f, 0.f, 0.f, 0.f, 0.f, 0.f, 0.f, 0.f};
    float f[8];
    bool haveSelf = false;

    for (int i = beg; i < end; i += 8) {
        int   sI[8];
        float wI[8];
        uint2 g[8];
#pragma unroll
        for (int u = 0; u < 8; ++u) {
            int valid = (i + u < end);
            int idx = valid ? (i + u) : i;
            sI[u] = ssrc[idx];
            wI[u] = valid ? snorm[idx] : 0.f;
        }
#pragma unroll
        for (int u = 0; u < 8; ++u) g[u] = Y[(size_t)sI[u] * 64 + lane];
        if (!haveSelf) {                        // consume self under batch-0 latency
            dec8(gs, f);
#pragma unroll
            for (int k = 0; k < 8; ++k) acc[k] = w0 * f[k];
            haveSelf = true;
        }
#pragma unroll
        for (int u = 0; u < 8; ++u) {
            dec8(g[u], f);
#pragma unroll
            for (int k = 0; k < 8; ++k) acc[k] = fmaf(wI[u], f[k], acc[k]);
        }
    }
    if (!haveSelf) {                            // deg == 0
        dec8(gs, f);
#pragma unroll
        for (int k = 0; k < 8; ++k) acc[k] = w0 * f[k];
    }

    float sv = 0.f;
#pragma unroll
    for (int k = 0; k < 8; ++k) {
        float o = fmaxf(fmaf(acc[k], invS, bv[k]), 0.f);
        accOut[k] = o;
        sv = fmaf(o, wv[k], sv);
    }
    sv += __shfl_down(sv, 4, 64);
    sv += __shfl_down(sv, 2, 64);
    sv += __shfl_down(sv, 1, 64);
    if ((lane & 7) == 0) {
        int b = lane >> 3;
        float* sp = sArr + (size_t)n * 8 + b;
        if (LAYER == 0) *sp = sv;
        else            *sp += sv;
    }
}

// ---------------- fused agg(L) + gemm(L+1): 8 nodes = 64 rows per block (proven R7) ----------------
template<int LAYER>
__global__ __launch_bounds__(256) void k_aggemm(const uint2* __restrict__ Yin,
                                                const int* __restrict__ rowoff,
                                                const int* __restrict__ ssrc,
                                                const float* __restrict__ snorm,
                                                const float* __restrict__ dinv,
                                                const float* __restrict__ bias,
                                                const float* __restrict__ fcW,
                                                float* __restrict__ sArr, float invS,
                                                const unsigned short* __restrict__ Wt,
                                                unsigned int* __restrict__ Yout, float Sout,
                                                int N, int rowsTot) {
    struct ShU { union { unsigned short sX[64 * 64]; float sOut[4][16 * 68]; }; };
    __shared__ ShU sh;
    int tid = threadIdx.x;
    int w = tid >> 6, lane = tid & 63;
    int b = lane >> 3, hb = (lane & 7) * 8;

    float bv[8], wv[8];
#pragma unroll
    for (int k = 0; k < 8; ++k) { bv[k] = bias[hb + k]; wv[k] = fcW[3 * (hb + k) + LAYER]; }

    int n0 = blockIdx.x * 8;
#pragma unroll
    for (int j = 0; j < 2; ++j) {
        int ln = w * 2 + j;
        int n = n0 + ln;
        int r = ln * 8 + b;
        unsigned int byte = (unsigned int)(r * 128 + hb * 2) ^ ((unsigned int)(r & 7) << 4);
        short8_t* dst = (short8_t*)((char*)sh.sX + byte);
        if (n < N) {
            float acc[8];
            agg_node<LAYER>(Yin, rowoff, ssrc, snorm, dinv, bv, wv, sArr, invS, n, lane, acc);
            ABFrag xr;
#pragma unroll
            for (int k = 0; k < 8; ++k) xr.u[k] = f2bf(acc[k]);
            *dst = xr.s;
        } else {
            ABFrag xr;
#pragma unroll
            for (int k = 0; k < 8; ++k) xr.u[k] = 0;
            *dst = xr.s;
        }
    }
    __syncthreads();

    // ---- GEMM on the block's 64 rows from LDS ----
    int cc = lane & 15, kg = (lane >> 4) * 8;
    ABFrag bf[2][4];
#pragma unroll
    for (int h = 0; h < 2; ++h)
#pragma unroll
        for (int c = 0; c < 4; ++c)
            bf[h][c].s = *(const short8_t*)&Wt[(size_t)(c * 16 + cc) * 64 + h * 32 + kg];

    int rA = w * 16 + (lane & 15);
    ABFrag a[2];
#pragma unroll
    for (int h = 0; h < 2; ++h) {
        unsigned int byte = (unsigned int)(rA * 128 + (h * 32 + kg) * 2) ^ ((unsigned int)(rA & 7) << 4);
        a[h].s = *(const short8_t*)((const char*)sh.sX + byte);
    }
    f32x4 acc4[4] = {f32x4{}, f32x4{}, f32x4{}, f32x4{}};
#pragma unroll
    for (int h = 0; h < 2; ++h)
#pragma unroll
        for (int c = 0; c < 4; ++c)
            acc4[c] = __builtin_amdgcn_mfma_f32_16x16x32_bf16(a[h].s, bf[h][c].s, acc4[c], 0, 0, 0);
    __syncthreads();   // all sX reads done before sOut (aliased) is written
    gemm_epilogue(&sh.sOut[w][0], acc4, Yout, Sout, blockIdx.x * 64 + w * 16, rowsTot, lane);
}

// ---------------- layer-3 aggregation (no following GEMM) ----------------

template<int LAYER>
__global__ __launch_bounds__(256) void k_agg(const uint2* __restrict__ Y,
                                             const int* __restrict__ rowoff,
                                             const int* __restrict__ ssrc,
                                             const float* __restrict__ snorm,
                                             const float* __restrict__ dinv,
                                             const float* __restrict__ bias,
                                             const float* __restrict__ fcW,
                                             float* __restrict__ sArr,
                                             float invS, int N) {
    int n = blockIdx.x * 4 + (threadIdx.x >> 6);
    if (n >= N) return;
    int lane = threadIdx.x & 63;
    int hb = (lane & 7) * 8;
    float bv[8], wv[8];
#pragma unroll
    for (int k = 0; k < 8; ++k) { bv[k] = bias[hb + k]; wv[k] = fcW[3 * (hb + k) + LAYER]; }
    float acc[8];
    agg_node<LAYER>(Y, rowoff, ssrc, snorm, dinv, bv, wv, sArr, invS, n, lane, acc);
}

// ---------------- pooling head (proven R2: one wave per column, 32 gathers in flight) ----------------

__global__ __launch_bounds__(64) void k_poolg(const float* __restrict__ sArr,
                                              const int* __restrict__ coff,
                                              const int* __restrict__ crow,
                                              float* __restrict__ hpoolT) {
    int c = blockIdx.x;
    int lane = threadIdx.x;
    int beg = coff[c], end = coff[c + 1];
    int b = lane & 7;
    float acc = 0.f;
    int i = beg + (lane >> 3);
    for (; i + 24 < end; i += 32) {
        int r0 = crow[i], r1 = crow[i + 8], r2 = crow[i + 16], r3 = crow[i + 24];
        float a0 = sArr[(size_t)r0 * 8 + b];
        float a1 = sArr[(size_t)r1 * 8 + b];
        float a2 = sArr[(size_t)r2 * 8 + b];
        float a3 = sArr[(size_t)r3 * 8 + b];
        acc += (a0 + a1) + (a2 + a3);
    }
    for (; i < end; i += 8) acc += sArr[(size_t)crow[i] * 8 + b];
    acc += __shfl_down(acc, 32, 64);
    acc += __shfl_down(acc, 16, 64);
    acc += __shfl_down(acc, 8, 64);
    if (lane < 8) {
        float inv = 1.f / fmaxf((float)(end - beg), 1.f);
        hpoolT[(size_t)c * 8 + b] = acc * inv;
    }
}

// ---------------- l1 partial + last-done head (proven R2) ----------------

__global__ __launch_bounds__(128) void k_l1f(const float* __restrict__ hpoolT,
                                             const float* __restrict__ fcb,
                                             const float* __restrict__ l1W,
                                             float* __restrict__ hpre,
                                             int* __restrict__ done,
                                             const float* __restrict__ l1b,
                                             const float* __restrict__ l2W,
                                             const float* __restrict__ l2b,
                                             float* __restrict__ out,
                                             int NC, int HFC, int bs, int NCLS,
                                             int CHUNK, int nBlocks) {
    __shared__ float hl[64];
    int b = blockIdx.y;
    int c0 = blockIdx.x * CHUNK;
    int j = threadIdx.x;
    int cend = min(c0 + CHUNK, NC);
    for (int c = c0 + j; c < cend; c += blockDim.x)
        hl[c - c0] = hpoolT[(size_t)c * 8 + b] + fcb[0];
    __syncthreads();
    float acc = 0.f;
    for (int c = c0; c < cend; ++c) acc = fmaf(hl[c - c0], l1W[(size_t)c * HFC + j], acc);
    atomicAdd(&hpre[(size_t)b * HFC + j], acc);

    __threadfence();
    __syncthreads();
    __shared__ int amLast;
    if (j == 0) amLast = (atomicAdd(done, 1) == nBlocks - 1);
    __syncthreads();
    if (!amLast) return;
    __threadfence();

    __shared__ float sZ[64];
    int g = j >> 3, l8 = j & 7;
    int nout = bs * NCLS;
    float v = 0.f;
    int b2 = g / NCLS, k2 = g - b2 * NCLS;
    if (g < nout) {
        for (int jj = l8; jj < HFC; jj += 8) {
            float h = fmaxf(hpre[(size_t)b2 * HFC + jj] + l1b[jj], 0.f);
            v = fmaf(h, l2W[(size_t)jj * NCLS + k2], v);
        }
    }
    v += __shfl_down(v, 4, 8);
    v += __shfl_down(v, 2, 8);
    v += __shfl_down(v, 1, 8);
    if (l8 == 0 && g < nout) sZ[g] = v + l2b[k2];
    __syncthreads();
    if (j < bs) {
        float m = -1e30f;
        for (int c = 0; c < NCLS; ++c) m = fmaxf(m, sZ[j * NCLS + c]);
        float s = 0.f;
        for (int c = 0; c < NCLS; ++c) s += expf(sZ[j * NCLS + c] - m);
        float lse = m + logf(s);
        for (int c = 0; c < NCLS; ++c) out[j * NCLS + c] = sZ[j * NCLS + c] - lse;
    }
}

// ---------------- launcher ----------------

extern "C" void kernel_launch(void* const* d_in, const int* in_sizes, int n_in,
                              void* d_out, int out_size, void* d_ws, size_t ws_size,
                              hipStream_t stream) {
    const float* x   = (const float*)d_in[0];
    const int* eidx  = (const int*)d_in[2];
    const int* prow  = (const int*)d_in[3];
    const int* pcol  = (const int*)d_in[4];
    const float* W1  = (const float*)d_in[5];
    const float* b1  = (const float*)d_in[6];
    const float* W2  = (const float*)d_in[7];
    const float* b2  = (const float*)d_in[8];
    const float* W3  = (const float*)d_in[9];
    const float* b3  = (const float*)d_in[10];
    const float* fcW = (const float*)d_in[11];
    const float* fcb = (const float*)d_in[12];
    const float* l1W = (const float*)d_in[13];
    const float* l1b = (const float*)d_in[14];
    const float* l2W = (const float*)d_in[15];
    const float* l2b = (const float*)d_in[16];
    float* out = (float*)d_out;

    const int bs   = in_sizes[1];                 // 8
    const int E    = in_sizes[2] / 2;
    const int P    = in_sizes[3];
    const int N    = in_sizes[0] / (bs * HID);
    const int HFC  = in_sizes[14];                // 128
    const int NC   = in_sizes[13] / HFC;          // 1000
    const int NCLS = in_sizes[15] / HFC;          // 2
    const int rows = N * bs;

    const int* esrc = eidx;
    const int* edst = eidx + E;

    size_t off = 0;
    auto alloc = [&](size_t bytes) -> void* {
        void* r = (char*)d_ws + off;
        off += (bytes + 255) & ~(size_t)255;
        return r;
    };
    // ---- zero region (one memset) ----
    char* zbase   = (char*)d_ws;
    int*   deg    = (int*)  alloc((size_t)N * 4);
    int*   fill   = (int*)  alloc((size_t)N * 4);
    int*   ccnt   = (int*)  alloc((size_t)NC * 4);
    int*   cfill  = (int*)  alloc((size_t)NC * 4);
    float* hpre   = (float*)alloc((size_t)bs * HFC * 4);
    int*   done   = (int*)  alloc(4);
    size_t zspan  = off;
    // ---- rest ----
    float* dinv   = (float*)alloc((size_t)N * 4);
    int*   rowoff = (int*)  alloc(((size_t)N + 1) * 4);
    int*   coff   = (int*)  alloc(((size_t)NC + 1) * 4);
    int*   crow   = (int*)  alloc((size_t)P * 4);
    float* hpoolT = (float*)alloc((size_t)NC * bs * 4);
    int*   ssrc   = (int*)  alloc((size_t)E * 4);
    float* snorm  = (float*)alloc((size_t)E * 4);
    unsigned int* Yqa  = (unsigned int*)alloc((size_t)rows * HID);
    unsigned int* Yqb  = (unsigned int*)alloc((size_t)rows * HID);
    float* sArr   = (float*)alloc((size_t)rows * 4);
    unsigned short* Wt = (unsigned short*)alloc((size_t)2 * 64 * 64 * 2);

    hipMemsetAsync(zbase, 0, zspan, stream);

    const float S1 = 1.f,  iS1 = 1.f;
    const float S2 = 16.f, iS2 = 1.f / 16.f;
    const float S3 = 128.f, iS3 = 1.f / 128.f;

    int gG2 = (rows + 127) / 128;   // 946
    int gF  = (N + 7) / 8;          // 1892 (aggemm blocks: 8 nodes = 64 rows)
    int gA  = (N + 3) / 4;
    int gPre = 512;

    // dispatch 1: GEMM1 (x, W1-via-LDS) || degree/col counts + Wt(W2,W3)
    k_fused1<<<gG2 + gPre, 256, 0, stream>>>(x, W1, Yqa, S1, N, rows, gG2,
                                             edst, deg, E, pcol, ccnt, P, W2, W3, Wt);
    k_pre_scan<<<64, 256, 0, stream>>>(deg, rowoff, N, ccnt, coff, NC, dinv);
    k_pre_scatter<<<gPre, 256, 0, stream>>>(esrc, edst, dinv, rowoff, fill, ssrc, snorm, E,
                                            prow, pcol, coff, cfill, crow, P);

    // fused agg1+gemm2 (Yqa -> Yqb), agg2+gemm3 (Yqb -> Yqa), agg3
    k_aggemm<0><<<gF, 256, 0, stream>>>((const uint2*)Yqa, rowoff, ssrc, snorm, dinv, b1, fcW,
                                        sArr, iS1, Wt, Yqb, S2, N, rows);
    k_aggemm<1><<<gF, 256, 0, stream>>>((const uint2*)Yqb, rowoff, ssrc, snorm, dinv, b2, fcW,
                                        sArr, iS2, Wt + 4096, Yqa, S3, N, rows);
    k_agg<2><<<gA, 256, 0, stream>>>((const uint2*)Yqa, rowoff, ssrc, snorm, dinv, b3, fcW,
                                     sArr, iS3, N);

    k_poolg<<<NC, 64, 0, stream>>>(sArr, coff, crow, hpoolT);

    const int CHUNK = 40;
    dim3 gL1((NC + CHUNK - 1) / CHUNK, bs);
    int nBlocks = gL1.x * gL1.y;   // 200
    k_l1f<<<gL1, 128, 0, stream>>>(hpoolT, fcb, l1W, hpre, done, l1b, l2W, l2b, out,
                                   NC, HFC, bs, NCLS, CHUNK, nBlocks);
}

// Round 9
// 317.287 us; speedup vs baseline: 3.1038x; 1.0310x over previous
//
#include <hip/hip_runtime.h>
#include <hip/hip_bf16.h>
#include <hip/hip_fp16.h>
#include <math.h>

#define HID 64

#if defined(__has_builtin)
#if __has_builtin(__builtin_amdgcn_cvt_pk_f32_fp8) && __has_builtin(__builtin_amdgcn_cvt_pk_fp8_f32)
#define HWFP8 1
#endif
#endif

typedef float vfloat2 __attribute__((ext_vector_type(2)));
typedef __attribute__((ext_vector_type(8))) short short8_t;   // 8 bf16 (4 VGPRs)
typedef __attribute__((ext_vector_type(4))) float f32x4;

union ABFrag { short8_t s; unsigned short u[8]; };

// ---------------- helpers ----------------

__device__ __forceinline__ unsigned short f2bf(float x) {
    unsigned int u = __float_as_uint(x);
    unsigned int r = u + 0x7fffu + ((u >> 16) & 1u);   // RNE
    return (unsigned short)(r >> 16);
}

#ifndef HWFP8
__device__ __forceinline__ unsigned int enc8_sw(float a) {
    unsigned short hb = __half_as_ushort(__float2half(a));
    unsigned int r = (unsigned int)hb + 0x7fu + ((hb >> 8) & 1u);
    return (r >> 8) & 0xffu;
}
__device__ __forceinline__ float dec8_sw(unsigned int b) {
    return __half2float(__ushort_as_half((unsigned short)(b << 8)));
}
#endif

__device__ __forceinline__ unsigned int enc4(float a, float b, float c, float d) {
#ifdef HWFP8
    int r = __builtin_amdgcn_cvt_pk_fp8_f32(a, b, 0, false);
    r = __builtin_amdgcn_cvt_pk_fp8_f32(c, d, r, true);
    return (unsigned int)r;
#else
    return enc8_sw(a) | (enc8_sw(b) << 8) | (enc8_sw(c) << 16) | (enc8_sw(d) << 24);
#endif
}

__device__ __forceinline__ void dec4(unsigned int w, float* f) {
#ifdef HWFP8
    vfloat2 a = __builtin_amdgcn_cvt_pk_f32_fp8((int)w, false);
    vfloat2 b = __builtin_amdgcn_cvt_pk_f32_fp8((int)w, true);
    f[0] = a.x; f[1] = a.y; f[2] = b.x; f[3] = b.y;
#else
    f[0] = dec8_sw(w & 0xffu); f[1] = dec8_sw((w >> 8) & 0xffu);
    f[2] = dec8_sw((w >> 16) & 0xffu); f[3] = dec8_sw(w >> 24);
#endif
}

__device__ __forceinline__ void dec8(uint2 g, float* f) {
    dec4(g.x, f);
    dec4(g.y, f + 4);
}

// ---------------- GEMM epilogue (per-wave LDS transpose + fp8 pack) ----------------
__device__ __forceinline__ void gemm_epilogue(float* so, const f32x4* acc,
                                              unsigned int* Yq, float S,
                                              int r0w, int rowsTot, int lane) {
    int cc = lane & 15;
    int cr = (lane >> 4) * 4;
#pragma unroll
    for (int c = 0; c < 4; ++c) {
        so[(cr + 0) * 68 + c * 16 + cc] = acc[c][0];
        so[(cr + 1) * 68 + c * 16 + cc] = acc[c][1];
        so[(cr + 2) * 68 + c * 16 + cc] = acc[c][2];
        so[(cr + 3) * 68 + c * 16 + cc] = acc[c][3];
    }
    __syncthreads();
#pragma unroll
    for (int i = 0; i < 4; ++i) {
        int idx = lane + i * 64;
        int row = idx >> 4, ci = idx & 15;
        int grow = r0w + row;
        if (grow < rowsTot) {
            float4 v = *(const float4*)&so[row * 68 + ci * 4];
            Yq[(size_t)grow * 16 + ci] = enc4(v.x * S, v.y * S, v.z * S, v.w * S);
        }
    }
}

// ---------------- fused dispatch 1: GEMM1 (x fp32, W1 via LDS) || pre-count ----------------
__global__ __launch_bounds__(256) void k_fused1(const float* __restrict__ x,
                                                const float* __restrict__ W1,
                                                unsigned int* __restrict__ Yq,
                                                float S, int N, int rowsTot, int gGf,
                                                const int* __restrict__ edst, int* __restrict__ deg, int E,
                                                const int* __restrict__ pcol, int* __restrict__ ccnt, int P,
                                                const float* __restrict__ W2, const float* __restrict__ W3,
                                                unsigned short* __restrict__ Wt) {
    __shared__ float sOut[4][16 * 68];
    __shared__ unsigned short sW[4096];   // W1 bf16, [c][k]
    int tid = threadIdx.x;
    if ((int)blockIdx.x < gGf) {
        int w = tid >> 6, lane = tid & 63;
        int cc = lane & 15, kg = (lane >> 4) * 8;
        float* so = &sOut[w][0];
#pragma unroll
        for (int i = 0; i < 16; ++i) {
            int idx = i * 256 + tid;
            int k = idx >> 6, c = idx & 63;
            sW[c * 64 + k] = f2bf(W1[idx]);
        }
        __syncthreads();
        ABFrag bf[2][4];
#pragma unroll
        for (int h = 0; h < 2; ++h)
#pragma unroll
            for (int c = 0; c < 4; ++c)
                bf[h][c].s = *(const short8_t*)&sW[(c * 16 + cc) * 64 + h * 32 + kg];

        int base = blockIdx.x * 128;
        ABFrag a[2];
        auto loadA = [&](int rA, ABFrag* dst) {
#pragma unroll
            for (int h = 0; h < 2; ++h) {
                if (rA < rowsTot) {
                    int n = rA >> 3, b = rA & 7;
                    const float* p = &x[((size_t)b * N + n) * 64 + h * 32 + kg];
                    float4 v0 = *(const float4*)p;
                    float4 v1 = *(const float4*)(p + 4);
                    dst[h].u[0] = f2bf(v0.x); dst[h].u[1] = f2bf(v0.y);
                    dst[h].u[2] = f2bf(v0.z); dst[h].u[3] = f2bf(v0.w);
                    dst[h].u[4] = f2bf(v1.x); dst[h].u[5] = f2bf(v1.y);
                    dst[h].u[6] = f2bf(v1.z); dst[h].u[7] = f2bf(v1.w);
                } else {
#pragma unroll
                    for (int j = 0; j < 8; ++j) dst[h].u[j] = 0;
                }
            }
        };
        loadA(base + w * 16 + (lane & 15), a);
#pragma unroll
        for (int t = 0; t < 2; ++t) {
            ABFrag an[2];
            if (t < 1) loadA(base + 64 + w * 16 + (lane & 15), an);
            f32x4 acc[4] = {f32x4{}, f32x4{}, f32x4{}, f32x4{}};
#pragma unroll
            for (int h = 0; h < 2; ++h)
#pragma unroll
                for (int c = 0; c < 4; ++c)
                    acc[c] = __builtin_amdgcn_mfma_f32_16x16x32_bf16(a[h].s, bf[h][c].s, acc[c], 0, 0, 0);
            gemm_epilogue(so, acc, Yq, S, base + t * 64 + w * 16, rowsTot, lane);
            if (t < 1) { a[0] = an[0]; a[1] = an[1]; __syncthreads(); }
        }
    } else {
        int cb = blockIdx.x - gGf;
        int nCB = gridDim.x - gGf;
        int gth = cb * 256 + tid;
        int GT = nCB * 256;
        for (int e = gth; e < E; e += GT) atomicAdd(&deg[edst[e]], 1);
        for (int p = gth; p < P; p += GT) atomicAdd(&ccnt[pcol[p]], 1);
        for (int i = gth; i < 2 * 4096; i += GT) {
            int l = i >> 12, r = i & 4095;
            int k = r >> 6, c = r & 63;
            const float* W = (l == 0) ? W2 : W3;
            Wt[(l << 12) + c * 64 + k] = f2bf(W[r]);
        }
    }
}

// ---------------- remaining preprocessing (proven R2) ----------------

__global__ __launch_bounds__(256) void k_pre_scan(const int* __restrict__ deg, int* __restrict__ rowoff, int N,
                                                  const int* __restrict__ ccnt, int* __restrict__ coff, int NC,
                                                  float* __restrict__ dinv) {
    __shared__ int part[256];
    int t = threadIdx.x;
    int gth = blockIdx.x * blockDim.x + t;
    int GT = gridDim.x * blockDim.x;
    for (int i = gth; i < N; i += GT) dinv[i] = rsqrtf((float)(deg[i] + 1));

    const int* cnt = nullptr; int* off = nullptr; int n = 0;
    if (blockIdx.x == 0)      { cnt = deg;  off = rowoff; n = N; }
    else if (blockIdx.x == 1) { cnt = ccnt; off = coff;   n = NC; }
    else return;

    int CH = (n + 255) >> 8;
    int lo = min(t * CH, n), hi = min(lo + CH, n);
    int sum = 0;
    for (int i = lo; i < hi; ++i) sum += cnt[i];
    part[t] = sum;
    __syncthreads();
    for (int o = 1; o < 256; o <<= 1) {
        int v = (t >= o) ? part[t - o] : 0;
        __syncthreads();
        part[t] += v;
        __syncthreads();
    }
    int run = (t == 0) ? 0 : part[t - 1];
    for (int i = lo; i < hi; ++i) { off[i] = run; run += cnt[i]; }
    if (t == 255) off[n] = run;
}

__global__ __launch_bounds__(256) void k_pre_scatter(const int* __restrict__ esrc, const int* __restrict__ edst,
                                                     const float* __restrict__ dinv, const int* __restrict__ rowoff,
                                                     int* __restrict__ fill, int* __restrict__ ssrc,
                                                     float* __restrict__ snorm, int E,
                                                     const int* __restrict__ prow, const int* __restrict__ pcol,
                                                     const int* __restrict__ coff, int* __restrict__ cfill,
                                                     int* __restrict__ crow, int P) {
    int gth = blockIdx.x * blockDim.x + threadIdx.x;
    int GT = gridDim.x * blockDim.x;
    for (int e = gth; e < E; e += GT) {
        int s = esrc[e], d = edst[e];
        int pos = rowoff[d] + atomicAdd(&fill[d], 1);
        ssrc[pos]  = s;
        snorm[pos] = dinv[s] * dinv[d];
    }
    for (int p = gth; p < P; p += GT) {
        int c = pcol[p];
        int pos = coff[c] + atomicAdd(&cfill[c], 1);
        crow[pos] = prow[p];
    }
}

// ---------------- agg core: coalesced edge metadata + shfl broadcast ----------------
// Edge lists are contiguous in CSR: one per-lane coalesced load fetches 64 edges'
// (src, weight); __shfl broadcasts each batch's values from registers (LDS pipe,
// no memory latency, overlaps the vector-memory gathers). Removes the 2 serial
// index-load round-trips per batch that R7 still had. Same batch-of-8 order,
// zero-weight padding (fmaf(0,f,acc)==acc; fp8 decodes always finite) -> bit-
// identical results.
template<int LAYER>
__device__ __forceinline__ void agg_node(const uint2* __restrict__ Y,
                                         const int* __restrict__ rowoff,
                                         const int* __restrict__ ssrc,
                                         const float* __restrict__ snorm,
                                         const float* __restrict__ dinv,
                                         const float* bv, const float* wv,
                                         float* __restrict__ sArr,
                                         float invS, int n, int lane,
                                         float* accOut) {
    float dn = dinv[n];
    float w0 = dn * dn;
    int beg = rowoff[n], end = rowoff[n + 1];

    uint2 gs = Y[(size_t)n * 64 + lane];       // self row: issue first
    float acc[8] = {0.f, 0.f, 0.f, 0.f, 0.f, 0.f, 0.f, 0.f};
    float f[8];
    bool haveSelf = false;

    for (int base = beg; base < end; base += 64) {
        int e = base + lane;
        int myIdx = (e < end) ? ssrc[e] : 0;       // coalesced: 64 edges/load
        float myW  = (e < end) ? snorm[e] : 0.f;
        int cnt = min(end - base, 64);
        for (int i = 0; i < cnt; i += 8) {
            int   sI[8];
            float wI[8];
            uint2 g[8];
#pragma unroll
            for (int u = 0; u < 8; ++u) {
                sI[u] = __shfl(myIdx, i + u, 64);   // register broadcast
                wI[u] = __shfl(myW,  i + u, 64);    // pad lanes carry w=0
            }
#pragma unroll
            for (int u = 0; u < 8; ++u) g[u] = Y[(size_t)sI[u] * 64 + lane];
            if (!haveSelf) {                        // consume self under batch-0 latency
                dec8(gs, f);
#pragma unroll
                for (int k = 0; k < 8; ++k) acc[k] = w0 * f[k];
                haveSelf = true;
            }
#pragma unroll
            for (int u = 0; u < 8; ++u) {
                dec8(g[u], f);
#pragma unroll
                for (int k = 0; k < 8; ++k) acc[k] = fmaf(wI[u], f[k], acc[k]);
            }
        }
    }
    if (!haveSelf) {                            // deg == 0
        dec8(gs, f);
#pragma unroll
        for (int k = 0; k < 8; ++k) acc[k] = w0 * f[k];
    }

    float sv = 0.f;
#pragma unroll
    for (int k = 0; k < 8; ++k) {
        float o = fmaxf(fmaf(acc[k], invS, bv[k]), 0.f);
        accOut[k] = o;
        sv = fmaf(o, wv[k], sv);
    }
    sv += __shfl_down(sv, 4, 64);
    sv += __shfl_down(sv, 2, 64);
    sv += __shfl_down(sv, 1, 64);
    if ((lane & 7) == 0) {
        int b = lane >> 3;
        float* sp = sArr + (size_t)n * 8 + b;
        if (LAYER == 0) *sp = sv;
        else            *sp += sv;
    }
}

// ---------------- fused agg(L) + gemm(L+1): 8 nodes = 64 rows per block (proven R7) ----------------
template<int LAYER>
__global__ __launch_bounds__(256) void k_aggemm(const uint2* __restrict__ Yin,
                                                const int* __restrict__ rowoff,
                                                const int* __restrict__ ssrc,
                                                const float* __restrict__ snorm,
                                                const float* __restrict__ dinv,
                                                const float* __restrict__ bias,
                                                const float* __restrict__ fcW,
                                                float* __restrict__ sArr, float invS,
                                                const unsigned short* __restrict__ Wt,
                                                unsigned int* __restrict__ Yout, float Sout,
                                                int N, int rowsTot) {
    struct ShU { union { unsigned short sX[64 * 64]; float sOut[4][16 * 68]; }; };
    __shared__ ShU sh;
    int tid = threadIdx.x;
    int w = tid >> 6, lane = tid & 63;
    int b = lane >> 3, hb = (lane & 7) * 8;

    float bv[8], wv[8];
#pragma unroll
    for (int k = 0; k < 8; ++k) { bv[k] = bias[hb + k]; wv[k] = fcW[3 * (hb + k) + LAYER]; }

    int n0 = blockIdx.x * 8;
#pragma unroll
    for (int j = 0; j < 2; ++j) {
        int ln = w * 2 + j;
        int n = n0 + ln;
        int r = ln * 8 + b;
        unsigned int byte = (unsigned int)(r * 128 + hb * 2) ^ ((unsigned int)(r & 7) << 4);
        short8_t* dst = (short8_t*)((char*)sh.sX + byte);
        if (n < N) {
            float acc[8];
            agg_node<LAYER>(Yin, rowoff, ssrc, snorm, dinv, bv, wv, sArr, invS, n, lane, acc);
            ABFrag xr;
#pragma unroll
            for (int k = 0; k < 8; ++k) xr.u[k] = f2bf(acc[k]);
            *dst = xr.s;
        } else {
            ABFrag xr;
#pragma unroll
            for (int k = 0; k < 8; ++k) xr.u[k] = 0;
            *dst = xr.s;
        }
    }
    __syncthreads();

    // ---- GEMM on the block's 64 rows from LDS ----
    int cc = lane & 15, kg = (lane >> 4) * 8;
    ABFrag bf[2][4];
#pragma unroll
    for (int h = 0; h < 2; ++h)
#pragma unroll
        for (int c = 0; c < 4; ++c)
            bf[h][c].s = *(const short8_t*)&Wt[(size_t)(c * 16 + cc) * 64 + h * 32 + kg];

    int rA = w * 16 + (lane & 15);
    ABFrag a[2];
#pragma unroll
    for (int h = 0; h < 2; ++h) {
        unsigned int byte = (unsigned int)(rA * 128 + (h * 32 + kg) * 2) ^ ((unsigned int)(rA & 7) << 4);
        a[h].s = *(const short8_t*)((const char*)sh.sX + byte);
    }
    f32x4 acc4[4] = {f32x4{}, f32x4{}, f32x4{}, f32x4{}};
#pragma unroll
    for (int h = 0; h < 2; ++h)
#pragma unroll
        for (int c = 0; c < 4; ++c)
            acc4[c] = __builtin_amdgcn_mfma_f32_16x16x32_bf16(a[h].s, bf[h][c].s, acc4[c], 0, 0, 0);
    __syncthreads();   // all sX reads done before sOut (aliased) is written
    gemm_epilogue(&sh.sOut[w][0], acc4, Yout, Sout, blockIdx.x * 64 + w * 16, rowsTot, lane);
}

// ---------------- layer-3 aggregation (no following GEMM) ----------------

template<int LAYER>
__global__ __launch_bounds__(256) void k_agg(const uint2* __restrict__ Y,
                                             const int* __restrict__ rowoff,
                                             const int* __restrict__ ssrc,
                                             const float* __restrict__ snorm,
                                             const float* __restrict__ dinv,
                                             const float* __restrict__ bias,
                                             const float* __restrict__ fcW,
                                             float* __restrict__ sArr,
                                             float invS, int N) {
    int n = blockIdx.x * 4 + (threadIdx.x >> 6);
    if (n >= N) return;
    int lane = threadIdx.x & 63;
    int hb = (lane & 7) * 8;
    float bv[8], wv[8];
#pragma unroll
    for (int k = 0; k < 8; ++k) { bv[k] = bias[hb + k]; wv[k] = fcW[3 * (hb + k) + LAYER]; }
    float acc[8];
    agg_node<LAYER>(Y, rowoff, ssrc, snorm, dinv, bv, wv, sArr, invS, n, lane, acc);
}

// ---------------- pooling head (proven R2: one wave per column, 32 gathers in flight) ----------------

__global__ __launch_bounds__(64) void k_poolg(const float* __restrict__ sArr,
                                              const int* __restrict__ coff,
                                              const int* __restrict__ crow,
                                              float* __restrict__ hpoolT) {
    int c = blockIdx.x;
    int lane = threadIdx.x;
    int beg = coff[c], end = coff[c + 1];
    int b = lane & 7;
    float acc = 0.f;
    int i = beg + (lane >> 3);
    for (; i + 24 < end; i += 32) {
        int r0 = crow[i], r1 = crow[i + 8], r2 = crow[i + 16], r3 = crow[i + 24];
        float a0 = sArr[(size_t)r0 * 8 + b];
        float a1 = sArr[(size_t)r1 * 8 + b];
        float a2 = sArr[(size_t)r2 * 8 + b];
        float a3 = sArr[(size_t)r3 * 8 + b];
        acc += (a0 + a1) + (a2 + a3);
    }
    for (; i < end; i += 8) acc += sArr[(size_t)crow[i] * 8 + b];
    acc += __shfl_down(acc, 32, 64);
    acc += __shfl_down(acc, 16, 64);
    acc += __shfl_down(acc, 8, 64);
    if (lane < 8) {
        float inv = 1.f / fmaxf((float)(end - beg), 1.f);
        hpoolT[(size_t)c * 8 + b] = acc * inv;
    }
}

// ---------------- l1 partial + last-done head (proven R2) ----------------

__global__ __launch_bounds__(128) void k_l1f(const float* __restrict__ hpoolT,
                                             const float* __restrict__ fcb,
                                             const float* __restrict__ l1W,
                                             float* __restrict__ hpre,
                                             int* __restrict__ done,
                                             const float* __restrict__ l1b,
                                             const float* __restrict__ l2W,
                                             const float* __restrict__ l2b,
                                             float* __restrict__ out,
                                             int NC, int HFC, int bs, int NCLS,
                                             int CHUNK, int nBlocks) {
    __shared__ float hl[64];
    int b = blockIdx.y;
    int c0 = blockIdx.x * CHUNK;
    int j = threadIdx.x;
    int cend = min(c0 + CHUNK, NC);
    for (int c = c0 + j; c < cend; c += blockDim.x)
        hl[c - c0] = hpoolT[(size_t)c * 8 + b] + fcb[0];
    __syncthreads();
    float acc = 0.f;
    for (int c = c0; c < cend; ++c) acc = fmaf(hl[c - c0], l1W[(size_t)c * HFC + j], acc);
    atomicAdd(&hpre[(size_t)b * HFC + j], acc);

    __threadfence();
    __syncthreads();
    __shared__ int amLast;
    if (j == 0) amLast = (atomicAdd(done, 1) == nBlocks - 1);
    __syncthreads();
    if (!amLast) return;
    __threadfence();

    __shared__ float sZ[64];
    int g = j >> 3, l8 = j & 7;
    int nout = bs * NCLS;
    float v = 0.f;
    int b2 = g / NCLS, k2 = g - b2 * NCLS;
    if (g < nout) {
        for (int jj = l8; jj < HFC; jj += 8) {
            float h = fmaxf(hpre[(size_t)b2 * HFC + jj] + l1b[jj], 0.f);
            v = fmaf(h, l2W[(size_t)jj * NCLS + k2], v);
        }
    }
    v += __shfl_down(v, 4, 8);
    v += __shfl_down(v, 2, 8);
    v += __shfl_down(v, 1, 8);
    if (l8 == 0 && g < nout) sZ[g] = v + l2b[k2];
    __syncthreads();
    if (j < bs) {
        float m = -1e30f;
        for (int c = 0; c < NCLS; ++c) m = fmaxf(m, sZ[j * NCLS + c]);
        float s = 0.f;
        for (int c = 0; c < NCLS; ++c) s += expf(sZ[j * NCLS + c] - m);
        float lse = m + logf(s);
        for (int c = 0; c < NCLS; ++c) out[j * NCLS + c] = sZ[j * NCLS + c] - lse;
    }
}

// ---------------- launcher ----------------

extern "C" void kernel_launch(void* const* d_in, const int* in_sizes, int n_in,
                              void* d_out, int out_size, void* d_ws, size_t ws_size,
                              hipStream_t stream) {
    const float* x   = (const float*)d_in[0];
    const int* eidx  = (const int*)d_in[2];
    const int* prow  = (const int*)d_in[3];
    const int* pcol  = (const int*)d_in[4];
    const float* W1  = (const float*)d_in[5];
    const float* b1  = (const float*)d_in[6];
    const float* W2  = (const float*)d_in[7];
    const float* b2  = (const float*)d_in[8];
    const float* W3  = (const float*)d_in[9];
    const float* b3  = (const float*)d_in[10];
    const float* fcW = (const float*)d_in[11];
    const float* fcb = (const float*)d_in[12];
    const float* l1W = (const float*)d_in[13];
    const float* l1b = (const float*)d_in[14];
    const float* l2W = (const float*)d_in[15];
    const float* l2b = (const float*)d_in[16];
    float* out = (float*)d_out;

    const int bs   = in_sizes[1];                 // 8
    const int E    = in_sizes[2] / 2;
    const int P    = in_sizes[3];
    const int N    = in_sizes[0] / (bs * HID);
    const int HFC  = in_sizes[14];                // 128
    const int NC   = in_sizes[13] / HFC;          // 1000
    const int NCLS = in_sizes[15] / HFC;          // 2
    const int rows = N * bs;

    const int* esrc = eidx;
    const int* edst = eidx + E;

    size_t off = 0;
    auto alloc = [&](size_t bytes) -> void* {
        void* r = (char*)d_ws + off;
        off += (bytes + 255) & ~(size_t)255;
        return r;
    };
    // ---- zero region (one memset) ----
    char* zbase   = (char*)d_ws;
    int*   deg    = (int*)  alloc((size_t)N * 4);
    int*   fill   = (int*)  alloc((size_t)N * 4);
    int*   ccnt   = (int*)  alloc((size_t)NC * 4);
    int*   cfill  = (int*)  alloc((size_t)NC * 4);
    float* hpre   = (float*)alloc((size_t)bs * HFC * 4);
    int*   done   = (int*)  alloc(4);
    size_t zspan  = off;
    // ---- rest ----
    float* dinv   = (float*)alloc((size_t)N * 4);
    int*   rowoff = (int*)  alloc(((size_t)N + 1) * 4);
    int*   coff   = (int*)  alloc(((size_t)NC + 1) * 4);
    int*   crow   = (int*)  alloc((size_t)P * 4);
    float* hpoolT = (float*)alloc((size_t)NC * bs * 4);
    int*   ssrc   = (int*)  alloc((size_t)E * 4);
    float* snorm  = (float*)alloc((size_t)E * 4);
    unsigned int* Yqa  = (unsigned int*)alloc((size_t)rows * HID);
    unsigned int* Yqb  = (unsigned int*)alloc((size_t)rows * HID);
    float* sArr   = (float*)alloc((size_t)rows * 4);
    unsigned short* Wt = (unsigned short*)alloc((size_t)2 * 64 * 64 * 2);

    hipMemsetAsync(zbase, 0, zspan, stream);

    const float S1 = 1.f,  iS1 = 1.f;
    const float S2 = 16.f, iS2 = 1.f / 16.f;
    const float S3 = 128.f, iS3 = 1.f / 128.f;

    int gG2 = (rows + 127) / 128;   // 946
    int gF  = (N + 7) / 8;          // 1892 (aggemm blocks: 8 nodes = 64 rows)
    int gA  = (N + 3) / 4;
    int gPre = 512;

    // dispatch 1: GEMM1 (x, W1-via-LDS) || degree/col counts + Wt(W2,W3)
    k_fused1<<<gG2 + gPre, 256, 0, stream>>>(x, W1, Yqa, S1, N, rows, gG2,
                                             edst, deg, E, pcol, ccnt, P, W2, W3, Wt);
    k_pre_scan<<<64, 256, 0, stream>>>(deg, rowoff, N, ccnt, coff, NC, dinv);
    k_pre_scatter<<<gPre, 256, 0, stream>>>(esrc, edst, dinv, rowoff, fill, ssrc, snorm, E,
                                            prow, pcol, coff, cfill, crow, P);

    // fused agg1+gemm2 (Yqa -> Yqb), agg2+gemm3 (Yqb -> Yqa), agg3
    k_aggemm<0><<<gF, 256, 0, stream>>>((const uint2*)Yqa, rowoff, ssrc, snorm, dinv, b1, fcW,
                                        sArr, iS1, Wt, Yqb, S2, N, rows);
    k_aggemm<1><<<gF, 256, 0, stream>>>((const uint2*)Yqb, rowoff, ssrc, snorm, dinv, b2, fcW,
                                        sArr, iS2, Wt + 4096, Yqa, S3, N, rows);
    k_agg<2><<<gA, 256, 0, stream>>>((const uint2*)Yqa, rowoff, ssrc, snorm, dinv, b3, fcW,
                                     sArr, iS3, N);

    k_poolg<<<NC, 64, 0, stream>>>(sArr, coff, crow, hpoolT);

    const int CHUNK = 40;
    dim3 gL1((NC + CHUNK - 1) / CHUNK, bs);
    int nBlocks = gL1.x * gL1.y;   // 200
    k_l1f<<<gL1, 128, 0, stream>>>(hpoolT, fcb, l1W, hpre, done, l1b, l2W, l2b, out,
                                   NC, HFC, bs, NCLS, CHUNK, nBlocks);
}